// Round 1
// baseline (613.143 us; speedup 1.0000x reference)
//
#include <hip/hip_runtime.h>
#include <math.h>

typedef unsigned short u16;
typedef __attribute__((ext_vector_type(8))) short s16x8;
typedef __attribute__((ext_vector_type(4))) float f32x4;

// ---------- constants ----------
#define B_  2
#define S_  2048
#define H_  2048
#define D_  128
#define NQ_ 16
#define NKV_ 4
#define M_  (B_*S_)        // 4096
#define NQKV_ 3072         // NQ*D + 2*NKV*D

__device__ __forceinline__ u16 f2bf(float x) {
  union { float f; unsigned u; } v; v.f = x;
  unsigned r = v.u + 0x7fffu + ((v.u >> 16) & 1u);
  return (u16)(r >> 16);
}

// ---------- elementwise fp32 -> bf16 ----------
__global__ __launch_bounds__(256) void cvt_x(const float* __restrict__ X, u16* __restrict__ Xb, long n4) {
  const f32x4* X4 = (const f32x4*)X;
  for (long i = (long)blockIdx.x*256 + threadIdx.x; i < n4; i += (long)gridDim.x*256) {
    f32x4 v = X4[i];
    union { u16 u[4]; unsigned long long ll; } p;
    p.u[0] = f2bf(v[0]); p.u[1] = f2bf(v[1]); p.u[2] = f2bf(v[2]); p.u[3] = f2bf(v[3]);
    ((unsigned long long*)Xb)[i] = p.ll;
  }
}

// ---------- transpose + convert: W [K][N] fp32 -> Wt [N][K] bf16 ----------
__global__ __launch_bounds__(256) void wtrans(const float* __restrict__ W, u16* __restrict__ Wt,
                                              int N, int K) {
  __shared__ float t[32][33];
  const int n0 = blockIdx.x*32, k0 = blockIdx.y*32;
  const int tx = threadIdx.x, ty = threadIdx.y;   // (32,8)
  #pragma unroll
  for (int i = 0; i < 32; i += 8) t[ty+i][tx] = W[(long)(k0+ty+i)*N + n0 + tx];
  __syncthreads();
  #pragma unroll
  for (int i = 0; i < 32; i += 8) Wt[(long)(n0+ty+i)*K + k0 + tx] = f2bf(t[tx][ty+i]);
}

// ---------- V transpose: QKV fp32 v-part -> Vt bf16 [B][NKV][D][S] ----------
__global__ __launch_bounds__(256) void vtrans(const float* __restrict__ QKV, u16* __restrict__ Vt) {
  __shared__ float t[32][33];
  const int bk = blockIdx.z;            // b*4+kvh
  const int s0 = blockIdx.x*32, d0 = blockIdx.y*32;
  const int tx = threadIdx.x, ty = threadIdx.y;
  const int b = bk >> 2, kvh = bk & 3;
  #pragma unroll
  for (int i = 0; i < 32; i += 8)
    t[ty+i][tx] = QKV[(long)(b*S_ + s0+ty+i)*NQKV_ + 2560 + kvh*128 + d0 + tx];
  __syncthreads();
  #pragma unroll
  for (int i = 0; i < 32; i += 8)
    Vt[((long)bk*D_ + d0+ty+i)*S_ + s0 + tx] = f2bf(t[tx][ty+i]);
}

// ---------- bias concat ----------
__global__ void concat_bias(const float* bq, const float* bk, const float* bv, float* bqkv) {
  int i = blockIdx.x*256 + threadIdx.x;
  if (i < NQKV_)
    bqkv[i] = (i < 2048) ? bq[i] : ((i < 2560) ? bk[i-2048] : bv[i-2560]);
}

// ---------- rope tables ----------
__global__ void rope_tab(float* __restrict__ cosb, float* __restrict__ sinb) {
  int i = blockIdx.x*256 + threadIdx.x;   // 2048*64
  int t = i >> 6, d = i & 63;
  float inv = powf(10000.0f, -((float)(2*d)) * (1.0f/128.0f));
  float fr = (float)t * inv;
  float sv, cv;
  sincosf(fr, &sv, &cv);
  cosb[i] = cv; sinb[i] = sv;
}

// ---------- rope apply + scatter to Q/K bf16, k/v fp32 outputs ----------
__global__ __launch_bounds__(256) void rope_qkv(
    const float* __restrict__ QKV, const float* __restrict__ cosb, const float* __restrict__ sinb,
    u16* __restrict__ Qb, u16* __restrict__ Kb,
    float* __restrict__ kout, float* __restrict__ vout)
{
  const int m = blockIdx.x;                 // b*S + s
  const int b = m >> 11, s = m & 2047;
  const int tid = threadIdx.x;
  const float* row = QKV + (long)m * NQKV_;
  const int d = tid & 63;
  const float c  = cosb[s*64 + d];
  const float sn = sinb[s*64 + d];
  #pragma unroll
  for (int i = 0; i < 4; i++) {             // 16 q heads
    int hh = (tid + i*256) >> 6;
    float x1 = row[hh*128 + d], x2 = row[hh*128 + d + 64];
    float o1 = x1*c - x2*sn, o2 = x2*c + x1*sn;
    long base = ((long)(b*NQ_ + hh)*S_ + s)*D_;
    Qb[base + d] = f2bf(o1);
    Qb[base + d + 64] = f2bf(o2);
  }
  {                                          // 4 k heads
    int kh = tid >> 6;
    float x1 = row[2048 + kh*128 + d], x2 = row[2048 + kh*128 + d + 64];
    float o1 = x1*c - x2*sn, o2 = x2*c + x1*sn;
    long kb = ((long)(b*NKV_ + kh)*S_ + s)*D_;
    Kb[kb + d] = f2bf(o1);
    Kb[kb + d + 64] = f2bf(o2);
    long ko = ((long)m*NKV_ + kh)*D_;
    kout[ko + d] = o1;
    kout[ko + d + 64] = o2;
  }
  #pragma unroll
  for (int i = 0; i < 2; i++) {              // v passthrough
    int e = tid + i*256;
    vout[(long)m*512 + e] = row[2560 + e];
  }
}

// ---------- GEMM: C[M][N] = A[M][K](bf16) * B^T (B stored [N][K] bf16) + bias ----------
__global__ __launch_bounds__(256) void gemm_bt(
    const u16* __restrict__ A, const u16* __restrict__ B,
    const float* __restrict__ bias, float* __restrict__ C,
    int M, int N, int K)
{
  __shared__ u16 As[128*32];
  __shared__ u16 Bs[128*32];
  const int tid = threadIdx.x;
  const int lane = tid & 63, w = tid >> 6;
  const int r16 = lane & 15, g = lane >> 4;
  const long m0 = (long)blockIdx.y * 128;
  const long n0 = (long)blockIdx.x * 128;
  const int wr = w >> 1, wc = w & 1;
  f32x4 acc[4][4] = {};

  const u16* Ag = A + m0 * K;
  const u16* Bg = B + n0 * K;

  for (int k0 = 0; k0 < K; k0 += 32) {
    #pragma unroll
    for (int it = 0; it < 2; it++) {
      int c = it*256 + w*64 + lane;
      const u16* ga = Ag + (long)(c >> 2) * K + k0 + (c & 3) * 8;
      __builtin_amdgcn_global_load_lds(
          (const __attribute__((address_space(1))) unsigned int*)ga,
          (__attribute__((address_space(3))) unsigned int*)&As[(it*256 + w*64)*8], 16, 0, 0);
      const u16* gb = Bg + (long)(c >> 2) * K + k0 + (c & 3) * 8;
      __builtin_amdgcn_global_load_lds(
          (const __attribute__((address_space(1))) unsigned int*)gb,
          (__attribute__((address_space(3))) unsigned int*)&Bs[(it*256 + w*64)*8], 16, 0, 0);
    }
    __syncthreads();
    s16x8 af[4], bf[4];
    #pragma unroll
    for (int mi = 0; mi < 4; mi++)
      af[mi] = *(const s16x8*)&As[(wr*64 + mi*16 + r16)*32 + g*8];
    #pragma unroll
    for (int nj = 0; nj < 4; nj++)
      bf[nj] = *(const s16x8*)&Bs[(wc*64 + nj*16 + r16)*32 + g*8];
    #pragma unroll
    for (int mi = 0; mi < 4; mi++)
      #pragma unroll
      for (int nj = 0; nj < 4; nj++)
        acc[mi][nj] = __builtin_amdgcn_mfma_f32_16x16x32_bf16(af[mi], bf[nj], acc[mi][nj], 0, 0, 0);
    __syncthreads();
  }

  #pragma unroll
  for (int mi = 0; mi < 4; mi++) {
    #pragma unroll
    for (int nj = 0; nj < 4; nj++) {
      int col = wc*64 + nj*16 + r16;
      float bv = bias[n0 + col];
      #pragma unroll
      for (int r = 0; r < 4; r++) {
        int row = wr*64 + mi*16 + g*4 + r;
        C[(m0 + row) * N + n0 + col] = acc[mi][nj][r] + bv;
      }
    }
  }
}

// ---------- flash attention: grid (S/64, NQ, B), 4 waves, 16 q-rows/wave ----------
__global__ __launch_bounds__(256) void attn_kernel(
    const u16* __restrict__ Qb, const u16* __restrict__ Kb,
    const u16* __restrict__ Vt, u16* __restrict__ Ob)
{
  __shared__ u16 Plds[4*16*48];          // per-wave P buffer, stride 48 (16B aligned)
  const int tid = threadIdx.x;
  const int lane = tid & 63, w = tid >> 6;
  const int r16 = lane & 15, g = lane >> 4;
  const int b = blockIdx.z, h = blockIdx.y, qt = blockIdx.x;
  const int kvh = h >> 2;
  const int q0 = qt*64 + w*16;
  const u16* Qg = Qb + (((long)(b*NQ_ + h))*S_ + q0)*D_;
  const u16* Kg = Kb + ((long)(b*NKV_ + kvh))*S_*D_;
  const u16* Vg = Vt + ((long)(b*NKV_ + kvh))*D_*S_;

  s16x8 qf[4];
  #pragma unroll
  for (int ks = 0; ks < 4; ks++)
    qf[ks] = *(const s16x8*)&Qg[r16*D_ + ks*32 + g*8];

  f32x4 po[8] = {};
  float mrow[4] = {-INFINITY,-INFINITY,-INFINITY,-INFINITY};
  float lrow[4] = {0.f,0.f,0.f,0.f};

  const int nsteps = (q0 + 15)/32 + 1;
  const float scale = 0.08838834764831845f;   // 1/sqrt(128)
  u16* pw = &Plds[w*768];

  for (int st = 0; st < nsteps; st++) {
    const int kv0 = st*32;
    f32x4 sc[2] = {};
    #pragma unroll
    for (int ct = 0; ct < 2; ct++)
      #pragma unroll
      for (int ks = 0; ks < 4; ks++) {
        s16x8 kf = *(const s16x8*)&Kg[(long)(kv0 + ct*16 + r16)*D_ + ks*32 + g*8];
        sc[ct] = __builtin_amdgcn_mfma_f32_16x16x32_bf16(qf[ks], kf, sc[ct], 0, 0, 0);
      }
    if (kv0 + 31 > q0) {         // causal mask needed (wave-uniform branch)
      #pragma unroll
      for (int ct = 0; ct < 2; ct++)
        #pragma unroll
        for (int r = 0; r < 4; r++) {
          int col = kv0 + ct*16 + r16, row = q0 + g*4 + r;
          sc[ct][r] = (col <= row) ? sc[ct][r]*scale : -INFINITY;
        }
    } else {
      #pragma unroll
      for (int ct = 0; ct < 2; ct++)
        #pragma unroll
        for (int r = 0; r < 4; r++) sc[ct][r] *= scale;
    }
    float pm[4];
    #pragma unroll
    for (int r = 0; r < 4; r++) pm[r] = fmaxf(sc[0][r], sc[1][r]);
    #pragma unroll
    for (int msk = 1; msk < 16; msk <<= 1)
      #pragma unroll
      for (int r = 0; r < 4; r++) pm[r] = fmaxf(pm[r], __shfl_xor(pm[r], msk, 64));
    float fr[4], mn[4], ps[4];
    #pragma unroll
    for (int r = 0; r < 4; r++) {
      mn[r] = fmaxf(mrow[r], pm[r]);
      fr[r] = __expf(mrow[r] - mn[r]);
      mrow[r] = mn[r];
    }
    #pragma unroll
    for (int r = 0; r < 4; r++) {
      float p0 = __expf(sc[0][r] - mn[r]);
      float p1 = __expf(sc[1][r] - mn[r]);
      sc[0][r] = p0; sc[1][r] = p1;
      ps[r] = p0 + p1;
    }
    #pragma unroll
    for (int msk = 1; msk < 16; msk <<= 1)
      #pragma unroll
      for (int r = 0; r < 4; r++) ps[r] += __shfl_xor(ps[r], msk, 64);
    #pragma unroll
    for (int r = 0; r < 4; r++) lrow[r] = lrow[r]*fr[r] + ps[r];
    #pragma unroll
    for (int dt = 0; dt < 8; dt++)
      #pragma unroll
      for (int r = 0; r < 4; r++) po[dt][r] *= fr[r];
    // P: C-layout -> LDS -> A-layout
    #pragma unroll
    for (int ct = 0; ct < 2; ct++)
      #pragma unroll
      for (int r = 0; r < 4; r++)
        pw[(g*4 + r)*48 + ct*16 + r16] = f2bf(sc[ct][r]);
    s16x8 pa = *(const s16x8*)&pw[r16*48 + g*8];
    #pragma unroll
    for (int dt = 0; dt < 8; dt++) {
      s16x8 vf = *(const s16x8*)&Vg[(long)(dt*16 + r16)*S_ + kv0 + g*8];
      po[dt] = __builtin_amdgcn_mfma_f32_16x16x32_bf16(pa, vf, po[dt], 0, 0, 0);
    }
  }
  float inv[4];
  #pragma unroll
  for (int r = 0; r < 4; r++) inv[r] = 1.0f / lrow[r];
  #pragma unroll
  for (int dt = 0; dt < 8; dt++)
    #pragma unroll
    for (int r = 0; r < 4; r++) {
      long m = (long)b*S_ + q0 + g*4 + r;
      Ob[m*H_ + h*D_ + dt*16 + r16] = f2bf(po[dt][r]*inv[r]);
    }
}

// ---------- launcher ----------
extern "C" void kernel_launch(void* const* d_in, const int* in_sizes, int n_in,
                              void* d_out, int out_size, void* d_ws, size_t ws_size,
                              hipStream_t stream) {
  const float* hs = (const float*)d_in[0];
  const float* Wq = (const float*)d_in[1];
  const float* bq = (const float*)d_in[2];
  const float* Wk = (const float*)d_in[3];
  const float* bk = (const float*)d_in[4];
  const float* Wv = (const float*)d_in[5];
  const float* bv = (const float*)d_in[6];
  const float* Wc = (const float*)d_in[7];
  const float* bc = (const float*)d_in[8];

  float* out  = (float*)d_out;                  // (B,S,H)
  float* kout = out + (long)M_*H_;              // (B,S,NKV,D)
  float* vout = kout + (long)M_*NKV_*D_;        // (B,S,NKV,D)

  char* ws = (char*)d_ws;
  u16*  Xbf   = (u16*)ws;                                   // [4096][2048]
  u16*  Wqkvt = Xbf + (long)M_*H_;                          // [3072][2048]
  u16*  Wct   = Wqkvt + (long)NQKV_*H_;                     // [2048][2048]
  float* bqkv = (float*)(Wct + (long)H_*H_);                // [3072]
  float* QKV  = bqkv + NQKV_;                               // [4096][3072]
  float* cosb = QKV + (long)M_*NQKV_;                       // [2048][64]
  float* sinb = cosb + S_*64;
  u16*  Qbf   = (u16*)(sinb + S_*64);                       // [B][NQ][S][D]
  u16*  Kbf   = Qbf + (long)B_*NQ_*S_*D_;                   // [B][NKV][S][D]
  u16*  Vtb   = Kbf + (long)B_*NKV_*S_*D_;                  // [B][NKV][D][S]
  u16*  Obf   = Vtb + (long)B_*NKV_*D_*S_;                  // [4096][2048]

  cvt_x<<<2048, 256, 0, stream>>>(hs, Xbf, (long)M_*H_/4);
  wtrans<<<dim3(64,64), dim3(32,8), 0, stream>>>(Wq, Wqkvt, 2048, 2048);
  wtrans<<<dim3(16,64), dim3(32,8), 0, stream>>>(Wk, Wqkvt + 2048L*2048, 512, 2048);
  wtrans<<<dim3(16,64), dim3(32,8), 0, stream>>>(Wv, Wqkvt + 2560L*2048, 512, 2048);
  wtrans<<<dim3(64,64), dim3(32,8), 0, stream>>>(Wc, Wct, 2048, 2048);
  concat_bias<<<12, 256, 0, stream>>>(bq, bk, bv, bqkv);
  rope_tab<<<512, 256, 0, stream>>>(cosb, sinb);

  gemm_bt<<<dim3(NQKV_/128, M_/128), 256, 0, stream>>>(Xbf, Wqkvt, bqkv, QKV, M_, NQKV_, H_);
  rope_qkv<<<M_, 256, 0, stream>>>(QKV, cosb, sinb, Qbf, Kbf, kout, vout);
  vtrans<<<dim3(S_/32, D_/32, B_*NKV_), dim3(32,8), 0, stream>>>(QKV, Vtb);
  attn_kernel<<<dim3(S_/64, NQ_, B_), 256, 0, stream>>>(Qbf, Kbf, Vtb, Obf);
  gemm_bt<<<dim3(H_/128, M_/128), 256, 0, stream>>>(Obf, Wct, bc, out, M_, H_, H_);
}

// Round 2
// 320.221 us; speedup vs baseline: 1.9148x; 1.9148x over previous
//
#include <hip/hip_runtime.h>
#include <math.h>

typedef unsigned short u16;
typedef __attribute__((ext_vector_type(8))) short s16x8;
typedef __attribute__((ext_vector_type(4))) float f32x4;
typedef __attribute__((ext_vector_type(2))) unsigned u32x2;

// ---------- constants ----------
#define B_  2
#define S_  2048
#define H_  2048
#define D_  128
#define NQ_ 16
#define NKV_ 4
#define M_  (B_*S_)        // 4096
#define NQKV_ 3072         // NQ*D + 2*NKV*D

__device__ __forceinline__ u16 f2bf(float x) {
  union { float f; unsigned u; } v; v.f = x;
  unsigned r = v.u + 0x7fffu + ((v.u >> 16) & 1u);
  return (u16)(r >> 16);
}

// ---------- elementwise fp32 -> bf16 ----------
__global__ __launch_bounds__(256) void cvt_x(const float* __restrict__ X, u16* __restrict__ Xb, long n4) {
  const f32x4* X4 = (const f32x4*)X;
  for (long i = (long)blockIdx.x*256 + threadIdx.x; i < n4; i += (long)gridDim.x*256) {
    f32x4 v = X4[i];
    union { u16 u[4]; unsigned long long ll; } p;
    p.u[0] = f2bf(v[0]); p.u[1] = f2bf(v[1]); p.u[2] = f2bf(v[2]); p.u[3] = f2bf(v[3]);
    ((unsigned long long*)Xb)[i] = p.ll;
  }
}

// ---------- transpose + convert: W [K][N] fp32 -> Wt [N][K] bf16 ----------
__global__ __launch_bounds__(256) void wtrans(const float* __restrict__ W, u16* __restrict__ Wt,
                                              int N, int K) {
  __shared__ float t[32][33];
  const int n0 = blockIdx.x*32, k0 = blockIdx.y*32;
  const int tx = threadIdx.x, ty = threadIdx.y;   // (32,8)
  #pragma unroll
  for (int i = 0; i < 32; i += 8) t[ty+i][tx] = W[(long)(k0+ty+i)*N + n0 + tx];
  __syncthreads();
  #pragma unroll
  for (int i = 0; i < 32; i += 8) Wt[(long)(n0+ty+i)*K + k0 + tx] = f2bf(t[tx][ty+i]);
}

// ---------- V transpose: QKV fp32 v-part -> Vt bf16 [B][NKV][D][S] ----------
__global__ __launch_bounds__(256) void vtrans(const float* __restrict__ QKV, u16* __restrict__ Vt) {
  __shared__ float t[32][33];
  const int bk = blockIdx.z;            // b*4+kvh
  const int s0 = blockIdx.x*32, d0 = blockIdx.y*32;
  const int tx = threadIdx.x, ty = threadIdx.y;
  const int b = bk >> 2, kvh = bk & 3;
  #pragma unroll
  for (int i = 0; i < 32; i += 8)
    t[ty+i][tx] = QKV[(long)(b*S_ + s0+ty+i)*NQKV_ + 2560 + kvh*128 + d0 + tx];
  __syncthreads();
  #pragma unroll
  for (int i = 0; i < 32; i += 8)
    Vt[((long)bk*D_ + d0+ty+i)*S_ + s0 + tx] = f2bf(t[tx][ty+i]);
}

// ---------- bias concat ----------
__global__ void concat_bias(const float* bq, const float* bk, const float* bv, float* bqkv) {
  int i = blockIdx.x*256 + threadIdx.x;
  if (i < NQKV_)
    bqkv[i] = (i < 2048) ? bq[i] : ((i < 2560) ? bk[i-2048] : bv[i-2560]);
}

// ---------- rope tables ----------
__global__ void rope_tab(float* __restrict__ cosb, float* __restrict__ sinb) {
  int i = blockIdx.x*256 + threadIdx.x;   // 2048*64
  int t = i >> 6, d = i & 63;
  float inv = powf(10000.0f, -((float)(2*d)) * (1.0f/128.0f));
  float fr = (float)t * inv;
  float sv, cv;
  sincosf(fr, &sv, &cv);
  cosb[i] = cv; sinb[i] = sv;
}

// ---------- rope apply + scatter to Q/K bf16, k/v fp32 outputs ----------
__global__ __launch_bounds__(256) void rope_qkv(
    const float* __restrict__ QKV, const float* __restrict__ cosb, const float* __restrict__ sinb,
    u16* __restrict__ Qb, u16* __restrict__ Kb,
    float* __restrict__ kout, float* __restrict__ vout)
{
  const int m = blockIdx.x;                 // b*S + s
  const int b = m >> 11, s = m & 2047;
  const int tid = threadIdx.x;
  const float* row = QKV + (long)m * NQKV_;
  const int d = tid & 63;
  const float c  = cosb[s*64 + d];
  const float sn = sinb[s*64 + d];
  #pragma unroll
  for (int i = 0; i < 4; i++) {             // 16 q heads
    int hh = (tid + i*256) >> 6;
    float x1 = row[hh*128 + d], x2 = row[hh*128 + d + 64];
    float o1 = x1*c - x2*sn, o2 = x2*c + x1*sn;
    long base = ((long)(b*NQ_ + hh)*S_ + s)*D_;
    Qb[base + d] = f2bf(o1);
    Qb[base + d + 64] = f2bf(o2);
  }
  {                                          // 4 k heads
    int kh = tid >> 6;
    float x1 = row[2048 + kh*128 + d], x2 = row[2048 + kh*128 + d + 64];
    float o1 = x1*c - x2*sn, o2 = x2*c + x1*sn;
    long kb = ((long)(b*NKV_ + kh)*S_ + s)*D_;
    Kb[kb + d] = f2bf(o1);
    Kb[kb + d + 64] = f2bf(o2);
    long ko = ((long)m*NKV_ + kh)*D_;
    kout[ko + d] = o1;
    kout[ko + d + 64] = o2;
  }
  #pragma unroll
  for (int i = 0; i < 2; i++) {              // v passthrough
    int e = tid + i*256;
    vout[(long)m*512 + e] = row[2560 + e];
  }
}

// ---------- GEMM: C[M][N] = A[M][K](bf16) * B^T (B stored [N][K] bf16) + bias ----------
__global__ __launch_bounds__(256) void gemm_bt(
    const u16* __restrict__ A, const u16* __restrict__ B,
    const float* __restrict__ bias, float* __restrict__ C,
    int M, int N, int K)
{
  __shared__ u16 As[128*32];
  __shared__ u16 Bs[128*32];
  const int tid = threadIdx.x;
  const int lane = tid & 63, w = tid >> 6;
  const int r16 = lane & 15, g = lane >> 4;
  const long m0 = (long)blockIdx.y * 128;
  const long n0 = (long)blockIdx.x * 128;
  const int wr = w >> 1, wc = w & 1;
  f32x4 acc[4][4] = {};

  const u16* Ag = A + m0 * K;
  const u16* Bg = B + n0 * K;

  for (int k0 = 0; k0 < K; k0 += 32) {
    #pragma unroll
    for (int it = 0; it < 2; it++) {
      int c = it*256 + w*64 + lane;
      const u16* ga = Ag + (long)(c >> 2) * K + k0 + (c & 3) * 8;
      __builtin_amdgcn_global_load_lds(
          (const __attribute__((address_space(1))) unsigned int*)ga,
          (__attribute__((address_space(3))) unsigned int*)&As[(it*256 + w*64)*8], 16, 0, 0);
      const u16* gb = Bg + (long)(c >> 2) * K + k0 + (c & 3) * 8;
      __builtin_amdgcn_global_load_lds(
          (const __attribute__((address_space(1))) unsigned int*)gb,
          (__attribute__((address_space(3))) unsigned int*)&Bs[(it*256 + w*64)*8], 16, 0, 0);
    }
    __syncthreads();
    s16x8 af[4], bf[4];
    #pragma unroll
    for (int mi = 0; mi < 4; mi++)
      af[mi] = *(const s16x8*)&As[(wr*64 + mi*16 + r16)*32 + g*8];
    #pragma unroll
    for (int nj = 0; nj < 4; nj++)
      bf[nj] = *(const s16x8*)&Bs[(wc*64 + nj*16 + r16)*32 + g*8];
    #pragma unroll
    for (int mi = 0; mi < 4; mi++)
      #pragma unroll
      for (int nj = 0; nj < 4; nj++)
        acc[mi][nj] = __builtin_amdgcn_mfma_f32_16x16x32_bf16(af[mi], bf[nj], acc[mi][nj], 0, 0, 0);
    __syncthreads();
  }

  #pragma unroll
  for (int mi = 0; mi < 4; mi++) {
    #pragma unroll
    for (int nj = 0; nj < 4; nj++) {
      int col = wc*64 + nj*16 + r16;
      float bv = bias[n0 + col];
      #pragma unroll
      for (int r = 0; r < 4; r++) {
        int row = wr*64 + mi*16 + g*4 + r;
        C[(m0 + row) * N + n0 + col] = acc[mi][nj][r] + bv;
      }
    }
  }
}

// ---------- flash attention v2 ----------
// grid: 512 linear blocks -> (b,h,qt) with work pairing; block = 4 waves x 32 q-rows (128-row tile)
// KVBLK=64 staged in LDS (global_load_lds, XOR-swizzled source), shared by all waves.
// Swapped QK^T: sc = mfma(K,Q) -> lane holds P[kv=g*4+r (+16ct)][q=r16]; in-register softmax.
__global__ __launch_bounds__(256) void attn_kernel(
    const u16* __restrict__ Qb, const u16* __restrict__ Kb,
    const u16* __restrict__ Vt, u16* __restrict__ Ob)
{
  __shared__ u16 Ks[64*128];      // [kv][k] swizzled
  __shared__ u16 Vs[128*64];      // [d][kv] swizzled
  __shared__ u16 Pw[4][32*72];    // per-wave P [q][kv], padded stride 72
  const int tid = threadIdx.x;
  const int lane = tid & 63, w = tid >> 6;
  const int r16 = lane & 15, g = lane >> 4;

  // block index -> (b, h, qt) with qt pairing for load balance
  const int l = blockIdx.x;
  const int hb = l >> 4;                 // 0..31
  const int b = hb >> 4, h = hb & 15;
  const int qsel = l & 15;
  const int qt = b ? (15 - qsel) : qsel; // paired blocks (l, l+256) sum to 15
  const int q0 = qt*128 + w*32;
  const int kvh = h >> 2;

  const u16* Qg = Qb + (((long)(b*NQ_ + h))*S_ + q0)*D_;
  const u16* Kg = Kb + ((long)(b*NKV_ + kvh))*S_*D_;
  const u16* Vg = Vt + ((long)(b*NKV_ + kvh))*D_*S_;

  // Q fragments (B-operand layout: row=r16, k contiguous at g*8)
  s16x8 qf[2][4];
  #pragma unroll
  for (int mi = 0; mi < 2; mi++)
    #pragma unroll
    for (int ks = 0; ks < 4; ks++)
      qf[mi][ks] = *(const s16x8*)&Qg[(mi*16 + r16)*D_ + ks*32 + g*8];

  f32x4 po[2][8] = {};
  float mrow[2] = {-1e30f, -1e30f};
  float lrow[2] = {0.f, 0.f};
  const int nt = 2*qt + 2;
  const float scale = 0.08838834764831845f;   // 1/sqrt(128)
  const int swz = (r16 & 7) << 3;             // element-granular XOR swizzle

  for (int st = 0; st < nt; st++) {
    const int kv0 = st*64;
    // ---- stage K tile [64][128] and V^T tile [128][64], swizzled source ----
    #pragma unroll
    for (int i = 0; i < 4; i++) {
      int slot = (w*4 + i)*64 + lane;
      int krow = slot >> 4;
      const u16* gk = Kg + (long)(kv0 + krow)*D_ + (((slot & 15)*8) ^ ((krow & 7) << 3));
      __builtin_amdgcn_global_load_lds(
          (const __attribute__((address_space(1))) unsigned int*)gk,
          (__attribute__((address_space(3))) unsigned int*)&Ks[(w*4 + i)*512], 16, 0, 0);
      int vrow = slot >> 3;
      const u16* gv = Vg + (long)vrow*S_ + kv0 + (((slot & 7)*8) ^ ((vrow & 7) << 3));
      __builtin_amdgcn_global_load_lds(
          (const __attribute__((address_space(1))) unsigned int*)gv,
          (__attribute__((address_space(3))) unsigned int*)&Vs[(w*4 + i)*512], 16, 0, 0);
    }
    __syncthreads();

    if (kv0 <= q0 + 31) {
      #pragma unroll
      for (int mi = 0; mi < 2; mi++) {
        if (kv0 > q0 + mi*16 + 15) continue;       // wave-uniform
        // ---- QK^T (swapped): sc[ct] = S[kv=ct*16+g*4+r][q=r16] ----
        f32x4 sc[4] = {{0,0,0,0},{0,0,0,0},{0,0,0,0},{0,0,0,0}};
        #pragma unroll
        for (int ct = 0; ct < 4; ct++)
          #pragma unroll
          for (int ks = 0; ks < 4; ks++) {
            s16x8 kf = *(const s16x8*)&Ks[(ct*16 + r16)*128 + ((ks*32 + g*8) ^ swz)];
            sc[ct] = __builtin_amdgcn_mfma_f32_16x16x32_bf16(kf, qf[mi][ks], sc[ct], 0, 0, 0);
          }
        // ---- scale + causal mask ----
        const int qrow = q0 + mi*16 + r16;
        #pragma unroll
        for (int ct = 0; ct < 4; ct++)
          #pragma unroll
          for (int rr = 0; rr < 4; rr++) {
            int kvg = kv0 + ct*16 + g*4 + rr;
            sc[ct][rr] = (kvg <= qrow) ? sc[ct][rr]*scale : -1e30f;
          }
        // ---- online softmax for row q=r16: in-register + 2 cross-lane ----
        float pm = sc[0][0];
        #pragma unroll
        for (int ct = 0; ct < 4; ct++)
          #pragma unroll
          for (int rr = 0; rr < 4; rr++) pm = fmaxf(pm, sc[ct][rr]);
        pm = fmaxf(pm, __shfl_xor(pm, 16, 64));
        pm = fmaxf(pm, __shfl_xor(pm, 32, 64));
        float mn = fmaxf(mrow[mi], pm);
        float fr = __expf(mrow[mi] - mn);
        mrow[mi] = mn;
        float ps = 0.f;
        #pragma unroll
        for (int ct = 0; ct < 4; ct++)
          #pragma unroll
          for (int rr = 0; rr < 4; rr++) {
            float p = __expf(sc[ct][rr] - mn);
            sc[ct][rr] = p; ps += p;
          }
        ps += __shfl_xor(ps, 16, 64);
        ps += __shfl_xor(ps, 32, 64);
        lrow[mi] = lrow[mi]*fr + ps;
        // ---- redistribute rescale factor to C-rows (q = g*4+rr) ----
        float frv[4];
        #pragma unroll
        for (int rr = 0; rr < 4; rr++) frv[rr] = __shfl(fr, g*4 + rr, 16);
        #pragma unroll
        for (int dt = 0; dt < 8; dt++)
          #pragma unroll
          for (int rr = 0; rr < 4; rr++) po[mi][dt][rr] *= frv[rr];
        // ---- write P[q=r16][kv] as packed b64, padded stride ----
        #pragma unroll
        for (int ct = 0; ct < 4; ct++) {
          u32x2 pk;
          pk[0] = (unsigned)f2bf(sc[ct][0]) | ((unsigned)f2bf(sc[ct][1]) << 16);
          pk[1] = (unsigned)f2bf(sc[ct][2]) | ((unsigned)f2bf(sc[ct][3]) << 16);
          *(u32x2*)&Pw[w][(mi*16 + r16)*72 + ct*16 + g*4] = pk;
        }
        // ---- PV: po += P * V^T ----
        #pragma unroll
        for (int ks2 = 0; ks2 < 2; ks2++) {
          s16x8 pa = *(const s16x8*)&Pw[w][(mi*16 + r16)*72 + ks2*32 + g*8];
          #pragma unroll
          for (int dt = 0; dt < 8; dt++) {
            s16x8 vf = *(const s16x8*)&Vs[(dt*16 + r16)*64 + ((ks2*32 + g*8) ^ swz)];
            po[mi][dt] = __builtin_amdgcn_mfma_f32_16x16x32_bf16(pa, vf, po[mi][dt], 0, 0, 0);
          }
        }
      }
    }
    __syncthreads();
  }

  // ---- epilogue: normalize and write O (bf16) ----
  #pragma unroll
  for (int mi = 0; mi < 2; mi++) {
    float inv = 1.0f / lrow[mi];
    float invq[4];
    #pragma unroll
    for (int rr = 0; rr < 4; rr++) invq[rr] = __shfl(inv, g*4 + rr, 16);
    #pragma unroll
    for (int dt = 0; dt < 8; dt++)
      #pragma unroll
      for (int rr = 0; rr < 4; rr++) {
        long q = q0 + mi*16 + g*4 + rr;
        Ob[((long)b*S_ + q)*H_ + h*D_ + dt*16 + r16] = f2bf(po[mi][dt][rr]*invq[rr]);
      }
  }
}

// ---------- launcher ----------
extern "C" void kernel_launch(void* const* d_in, const int* in_sizes, int n_in,
                              void* d_out, int out_size, void* d_ws, size_t ws_size,
                              hipStream_t stream) {
  const float* hs = (const float*)d_in[0];
  const float* Wq = (const float*)d_in[1];
  const float* bq = (const float*)d_in[2];
  const float* Wk = (const float*)d_in[3];
  const float* bk = (const float*)d_in[4];
  const float* Wv = (const float*)d_in[5];
  const float* bv = (const float*)d_in[6];
  const float* Wc = (const float*)d_in[7];
  const float* bc = (const float*)d_in[8];

  float* out  = (float*)d_out;                  // (B,S,H)
  float* kout = out + (long)M_*H_;              // (B,S,NKV,D)
  float* vout = kout + (long)M_*NKV_*D_;        // (B,S,NKV,D)

  char* ws = (char*)d_ws;
  u16*  Xbf   = (u16*)ws;                                   // [4096][2048]
  u16*  Wqkvt = Xbf + (long)M_*H_;                          // [3072][2048]
  u16*  Wct   = Wqkvt + (long)NQKV_*H_;                     // [2048][2048]
  float* bqkv = (float*)(Wct + (long)H_*H_);                // [3072]
  float* QKV  = bqkv + NQKV_;                               // [4096][3072]
  float* cosb = QKV + (long)M_*NQKV_;                       // [2048][64]
  float* sinb = cosb + S_*64;
  u16*  Qbf   = (u16*)(sinb + S_*64);                       // [B][NQ][S][D]
  u16*  Kbf   = Qbf + (long)B_*NQ_*S_*D_;                   // [B][NKV][S][D]
  u16*  Vtb   = Kbf + (long)B_*NKV_*S_*D_;                  // [B][NKV][D][S]
  u16*  Obf   = Vtb + (long)B_*NKV_*D_*S_;                  // [4096][2048]

  cvt_x<<<2048, 256, 0, stream>>>(hs, Xbf, (long)M_*H_/4);
  wtrans<<<dim3(64,64), dim3(32,8), 0, stream>>>(Wq, Wqkvt, 2048, 2048);
  wtrans<<<dim3(16,64), dim3(32,8), 0, stream>>>(Wk, Wqkvt + 2048L*2048, 512, 2048);
  wtrans<<<dim3(16,64), dim3(32,8), 0, stream>>>(Wv, Wqkvt + 2560L*2048, 512, 2048);
  wtrans<<<dim3(64,64), dim3(32,8), 0, stream>>>(Wc, Wct, 2048, 2048);
  concat_bias<<<12, 256, 0, stream>>>(bq, bk, bv, bqkv);
  rope_tab<<<512, 256, 0, stream>>>(cosb, sinb);

  gemm_bt<<<dim3(NQKV_/128, M_/128), 256, 0, stream>>>(Xbf, Wqkvt, bqkv, QKV, M_, NQKV_, H_);
  rope_qkv<<<M_, 256, 0, stream>>>(QKV, cosb, sinb, Qbf, Kbf, kout, vout);
  vtrans<<<dim3(S_/32, D_/32, B_*NKV_), dim3(32,8), 0, stream>>>(QKV, Vtb);
  attn_kernel<<<dim3(512), 256, 0, stream>>>(Qbf, Kbf, Vtb, Obf);
  gemm_bt<<<dim3(H_/128, M_/128), 256, 0, stream>>>(Obf, Wct, bc, out, M_, H_, H_);
}

// Round 3
// 281.306 us; speedup vs baseline: 2.1796x; 1.1383x over previous
//
#include <hip/hip_runtime.h>
#include <math.h>

typedef unsigned short u16;
typedef __attribute__((ext_vector_type(8))) short s16x8;
typedef __attribute__((ext_vector_type(4))) float f32x4;
typedef __attribute__((ext_vector_type(2))) unsigned u32x2;

// ---------- constants ----------
#define B_  2
#define S_  2048
#define H_  2048
#define D_  128
#define NQ_ 16
#define NKV_ 4
#define M_  (B_*S_)        // 4096
#define NQKV_ 3072         // NQ*D + 2*NKV*D

#define MFMA16(a,b,c) __builtin_amdgcn_mfma_f32_16x16x32_bf16(a,b,c,0,0,0)

__device__ __forceinline__ u16 f2bf(float x) {
  union { float f; unsigned u; } v; v.f = x;
  unsigned r = v.u + 0x7fffu + ((v.u >> 16) & 1u);
  return (u16)(r >> 16);
}

// ---------- elementwise fp32 -> bf16 ----------
__global__ __launch_bounds__(256) void cvt_x(const float* __restrict__ X, u16* __restrict__ Xb, long n4) {
  const f32x4* X4 = (const f32x4*)X;
  for (long i = (long)blockIdx.x*256 + threadIdx.x; i < n4; i += (long)gridDim.x*256) {
    f32x4 v = X4[i];
    union { u16 u[4]; unsigned long long ll; } p;
    p.u[0] = f2bf(v[0]); p.u[1] = f2bf(v[1]); p.u[2] = f2bf(v[2]); p.u[3] = f2bf(v[3]);
    ((unsigned long long*)Xb)[i] = p.ll;
  }
}

// ---------- transpose + convert: W [K][N] fp32 -> Wt [N][K] bf16 ----------
__global__ __launch_bounds__(256) void wtrans(const float* __restrict__ W, u16* __restrict__ Wt,
                                              int N, int K) {
  __shared__ float t[32][33];
  const int n0 = blockIdx.x*32, k0 = blockIdx.y*32;
  const int tx = threadIdx.x, ty = threadIdx.y;   // (32,8)
  #pragma unroll
  for (int i = 0; i < 32; i += 8) t[ty+i][tx] = W[(long)(k0+ty+i)*N + n0 + tx];
  __syncthreads();
  #pragma unroll
  for (int i = 0; i < 32; i += 8) Wt[(long)(n0+ty+i)*K + k0 + tx] = f2bf(t[tx][ty+i]);
}

// ---------- V transpose: QKV fp32 v-part -> Vt bf16 [B][NKV][D][S] ----------
__global__ __launch_bounds__(256) void vtrans(const float* __restrict__ QKV, u16* __restrict__ Vt) {
  __shared__ float t[32][33];
  const int bk = blockIdx.z;            // b*4+kvh
  const int s0 = blockIdx.x*32, d0 = blockIdx.y*32;
  const int tx = threadIdx.x, ty = threadIdx.y;
  const int b = bk >> 2, kvh = bk & 3;
  #pragma unroll
  for (int i = 0; i < 32; i += 8)
    t[ty+i][tx] = QKV[(long)(b*S_ + s0+ty+i)*NQKV_ + 2560 + kvh*128 + d0 + tx];
  __syncthreads();
  #pragma unroll
  for (int i = 0; i < 32; i += 8)
    Vt[((long)bk*D_ + d0+ty+i)*S_ + s0 + tx] = f2bf(t[tx][ty+i]);
}

// ---------- bias concat ----------
__global__ void concat_bias(const float* bq, const float* bk, const float* bv, float* bqkv) {
  int i = blockIdx.x*256 + threadIdx.x;
  if (i < NQKV_)
    bqkv[i] = (i < 2048) ? bq[i] : ((i < 2560) ? bk[i-2048] : bv[i-2560]);
}

// ---------- rope tables ----------
__global__ void rope_tab(float* __restrict__ cosb, float* __restrict__ sinb) {
  int i = blockIdx.x*256 + threadIdx.x;   // 2048*64
  int t = i >> 6, d = i & 63;
  float inv = powf(10000.0f, -((float)(2*d)) * (1.0f/128.0f));
  float fr = (float)t * inv;
  float sv, cv;
  sincosf(fr, &sv, &cv);
  cosb[i] = cv; sinb[i] = sv;
}

// ---------- rope apply + scatter; Q pre-scaled by 1/sqrt(D)*log2(e) for exp2-domain softmax ----------
__global__ __launch_bounds__(256) void rope_qkv(
    const float* __restrict__ QKV, const float* __restrict__ cosb, const float* __restrict__ sinb,
    u16* __restrict__ Qb, u16* __restrict__ Kb,
    float* __restrict__ kout, float* __restrict__ vout)
{
  const float QS = 0.08838834764831845f * 1.4426950408889634f;
  const int m = blockIdx.x;                 // b*S + s
  const int b = m >> 11, s = m & 2047;
  const int tid = threadIdx.x;
  const float* row = QKV + (long)m * NQKV_;
  const int d = tid & 63;
  const float c  = cosb[s*64 + d];
  const float sn = sinb[s*64 + d];
  #pragma unroll
  for (int i = 0; i < 4; i++) {             // 16 q heads
    int hh = (tid + i*256) >> 6;
    float x1 = row[hh*128 + d], x2 = row[hh*128 + d + 64];
    float o1 = x1*c - x2*sn, o2 = x2*c + x1*sn;
    long base = ((long)(b*NQ_ + hh)*S_ + s)*D_;
    Qb[base + d] = f2bf(o1*QS);
    Qb[base + d + 64] = f2bf(o2*QS);
  }
  {                                          // 4 k heads
    int kh = tid >> 6;
    float x1 = row[2048 + kh*128 + d], x2 = row[2048 + kh*128 + d + 64];
    float o1 = x1*c - x2*sn, o2 = x2*c + x1*sn;
    long kb = ((long)(b*NKV_ + kh)*S_ + s)*D_;
    Kb[kb + d] = f2bf(o1);
    Kb[kb + d + 64] = f2bf(o2);
    long ko = ((long)m*NKV_ + kh)*D_;
    kout[ko + d] = o1;
    kout[ko + d + 64] = o2;
  }
  #pragma unroll
  for (int i = 0; i < 2; i++) {              // v passthrough
    int e = tid + i*256;
    vout[(long)m*512 + e] = row[2560 + e];
  }
}

// ---------- GEMM: C[M][N] = A[M][K](bf16) * B^T (B stored [N][K] bf16) + bias ----------
__global__ __launch_bounds__(256) void gemm_bt(
    const u16* __restrict__ A, const u16* __restrict__ B,
    const float* __restrict__ bias, float* __restrict__ C,
    int M, int N, int K)
{
  __shared__ u16 As[128*32];
  __shared__ u16 Bs[128*32];
  const int tid = threadIdx.x;
  const int lane = tid & 63, w = tid >> 6;
  const int r16 = lane & 15, g = lane >> 4;
  // XCD-aware bijective block swizzle (nwg % 8 == 0 for both call sites)
  const int gx = gridDim.x;
  const int nwg = gx * gridDim.y;
  const int id = blockIdx.y * gx + blockIdx.x;
  const int cpx = nwg >> 3;
  const int sid = (id & 7) * cpx + (id >> 3);
  const long m0 = (long)(sid / gx) * 128;
  const long n0 = (long)(sid % gx) * 128;
  const int wr = w >> 1, wc = w & 1;
  f32x4 acc[4][4] = {};

  const u16* Ag = A + m0 * K;
  const u16* Bg = B + n0 * K;

  for (int k0 = 0; k0 < K; k0 += 32) {
    #pragma unroll
    for (int it = 0; it < 2; it++) {
      int c = it*256 + w*64 + lane;
      const u16* ga = Ag + (long)(c >> 2) * K + k0 + (c & 3) * 8;
      __builtin_amdgcn_global_load_lds(
          (const __attribute__((address_space(1))) unsigned int*)ga,
          (__attribute__((address_space(3))) unsigned int*)&As[(it*256 + w*64)*8], 16, 0, 0);
      const u16* gb = Bg + (long)(c >> 2) * K + k0 + (c & 3) * 8;
      __builtin_amdgcn_global_load_lds(
          (const __attribute__((address_space(1))) unsigned int*)gb,
          (__attribute__((address_space(3))) unsigned int*)&Bs[(it*256 + w*64)*8], 16, 0, 0);
    }
    __syncthreads();
    s16x8 af[4], bf[4];
    #pragma unroll
    for (int mi = 0; mi < 4; mi++)
      af[mi] = *(const s16x8*)&As[(wr*64 + mi*16 + r16)*32 + g*8];
    #pragma unroll
    for (int nj = 0; nj < 4; nj++)
      bf[nj] = *(const s16x8*)&Bs[(wc*64 + nj*16 + r16)*32 + g*8];
    #pragma unroll
    for (int mi = 0; mi < 4; mi++)
      #pragma unroll
      for (int nj = 0; nj < 4; nj++)
        acc[mi][nj] = MFMA16(af[mi], bf[nj], acc[mi][nj]);
    __syncthreads();
  }

  #pragma unroll
  for (int mi = 0; mi < 4; mi++) {
    #pragma unroll
    for (int nj = 0; nj < 4; nj++) {
      int col = wc*64 + nj*16 + r16;
      float bv = bias[n0 + col];
      #pragma unroll
      for (int r = 0; r < 4; r++) {
        int row = wr*64 + mi*16 + g*4 + r;
        C[(m0 + row) * N + n0 + col] = acc[mi][nj][r] + bv;
      }
    }
  }
}

// ---------- flash attention v3 ----------
// 256 blocks (1/CU), each: (b,h) x paired q-tiles (qt, 15-qt) of 128 rows, 4 waves x 32 rows.
// Double-buffered K/V LDS staging (global_load_lds + counted vmcnt + raw s_barrier).
// Swapped QK^T, exp2-domain softmax (Q pre-scaled), defer-max THR=8, conflict-free P buffer.
__global__ __launch_bounds__(256, 1) void attn_kernel(
    const u16* __restrict__ Qb, const u16* __restrict__ Kb,
    const u16* __restrict__ Vt, u16* __restrict__ Ob)
{
  __shared__ u16 Ks[2][64*128];      // [kv][d] swizzled
  __shared__ u16 Vs[2][128*64];      // [d][kv] swizzled
  __shared__ u16 Pp[4][2][1024];     // per-wave,mi: [ct][q16][16elem]
  const int tid = threadIdx.x;
  const int lane = tid & 63, w = tid >> 6;
  const int r16 = lane & 15, g = lane >> 4;
  const int l = blockIdx.x;          // 256 blocks
  const int bh = l >> 3;             // 0..31
  const int b = bh >> 4, h = bh & 15;
  const int pr = l & 7;
  const int kvh = h >> 2;
  const u16* Kg = Kb + ((long)(b*NKV_ + kvh))*S_*D_;
  const u16* Vg = Vt + ((long)(b*NKV_ + kvh))*D_*S_;
  const int swz = (r16 & 7) << 3;

  auto stage = [&](int buf, int kv0s) {
    #pragma unroll
    for (int i = 0; i < 4; i++) {
      const int slot = (w*4 + i)*64 + lane;
      const int krow = slot >> 4;
      const u16* gk = Kg + (long)(kv0s + krow)*D_ + (((slot & 15)*8) ^ ((krow & 7) << 3));
      __builtin_amdgcn_global_load_lds(
          (const __attribute__((address_space(1))) unsigned int*)gk,
          (__attribute__((address_space(3))) unsigned int*)&Ks[buf][(w*4 + i)*512], 16, 0, 0);
      const int vrow = slot >> 3;
      const u16* gv = Vg + (long)vrow*S_ + kv0s + (((slot & 7)*8) ^ ((vrow & 7) << 3));
      __builtin_amdgcn_global_load_lds(
          (const __attribute__((address_space(1))) unsigned int*)gv,
          (__attribute__((address_space(3))) unsigned int*)&Vs[buf][(w*4 + i)*512], 16, 0, 0);
    }
  };

  for (int pass = 0; pass < 2; pass++) {
    const int qt = pass ? (15 - pr) : pr;
    const int q0 = qt*128 + w*32;
    const int nt = 2*qt + 2;
    const u16* Qg = Qb + (((long)(b*NQ_ + h))*S_ + q0)*D_;
    s16x8 qf[2][4];
    #pragma unroll
    for (int mi = 0; mi < 2; mi++)
      #pragma unroll
      for (int ks = 0; ks < 4; ks++)
        qf[mi][ks] = *(const s16x8*)&Qg[(mi*16 + r16)*D_ + ks*32 + g*8];
    f32x4 po[2][8] = {};
    float mrow[2] = {-1e30f, -1e30f};
    float lrow[2] = {0.f, 0.f};

    stage(0, 0);
    for (int t = 0; t < nt; t++) {
      const int cur = t & 1;
      const int kv0 = t*64;
      if (t + 1 < nt) {
        stage(cur ^ 1, kv0 + 64);
        asm volatile("s_waitcnt vmcnt(8)" ::: "memory");
      } else {
        asm volatile("s_waitcnt vmcnt(0)" ::: "memory");
      }
      __builtin_amdgcn_s_barrier();

      if (kv0 <= q0 + 31) {
        const bool act0 = (kv0 <= q0 + 15);
        // ---- QK^T (swapped), K fragment shared across mi ----
        f32x4 sc[2][4] = {};
        #pragma unroll
        for (int ct = 0; ct < 4; ct++)
          #pragma unroll
          for (int ks = 0; ks < 4; ks++) {
            s16x8 kf = *(const s16x8*)&Ks[cur][(ct*16 + r16)*128 + ((ks*32 + g*8) ^ swz)];
            if (act0) sc[0][ct] = MFMA16(kf, qf[0][ks], sc[0][ct]);
            sc[1][ct] = MFMA16(kf, qf[1][ks], sc[1][ct]);
          }
        // ---- per-mi softmax (exp2 domain) + P store ----
        #pragma unroll
        for (int mi = 0; mi < 2; mi++) {
          if (mi == 0 && !act0) continue;
          if (kv0 + 63 > q0 + mi*16) {                 // masking needed
            const int qrow = q0 + mi*16 + r16;
            #pragma unroll
            for (int ct = 0; ct < 4; ct++)
              #pragma unroll
              for (int rr = 0; rr < 4; rr++)
                if (kv0 + ct*16 + g*4 + rr > qrow) sc[mi][ct][rr] = -3.0e38f;
          }
          float a0 = fmaxf(fmaxf(sc[mi][0][0], sc[mi][0][1]), fmaxf(sc[mi][0][2], sc[mi][0][3]));
          float a1 = fmaxf(fmaxf(sc[mi][1][0], sc[mi][1][1]), fmaxf(sc[mi][1][2], sc[mi][1][3]));
          float a2 = fmaxf(fmaxf(sc[mi][2][0], sc[mi][2][1]), fmaxf(sc[mi][2][2], sc[mi][2][3]));
          float a3 = fmaxf(fmaxf(sc[mi][3][0], sc[mi][3][1]), fmaxf(sc[mi][3][2], sc[mi][3][3]));
          float pm = fmaxf(fmaxf(a0, a1), fmaxf(a2, a3));
          pm = fmaxf(pm, __shfl_xor(pm, 16, 64));
          pm = fmaxf(pm, __shfl_xor(pm, 32, 64));
          float mn = mrow[mi];
          if (!__all(pm - mn <= 8.0f)) {               // defer-max (T13)
            mn = fmaxf(mn, pm);
            float fr = exp2f(mrow[mi] - mn);
            mrow[mi] = mn;
            lrow[mi] *= fr;
            float frv[4];
            #pragma unroll
            for (int rr = 0; rr < 4; rr++) frv[rr] = __shfl(fr, g*4 + rr, 16);
            #pragma unroll
            for (int dt = 0; dt < 8; dt++)
              #pragma unroll
              for (int rr = 0; rr < 4; rr++) po[mi][dt][rr] *= frv[rr];
          }
          float ps = 0.f;
          #pragma unroll
          for (int ct = 0; ct < 4; ct++)
            #pragma unroll
            for (int rr = 0; rr < 4; rr++) {
              float p = exp2f(sc[mi][ct][rr] - mn);
              sc[mi][ct][rr] = p;
              ps += p;
            }
          ps += __shfl_xor(ps, 16, 64);
          ps += __shfl_xor(ps, 32, 64);
          lrow[mi] += ps;
          #pragma unroll
          for (int ct = 0; ct < 4; ct++) {
            u32x2 pk;
            pk[0] = (unsigned)f2bf(sc[mi][ct][0]) | ((unsigned)f2bf(sc[mi][ct][1]) << 16);
            pk[1] = (unsigned)f2bf(sc[mi][ct][2]) | ((unsigned)f2bf(sc[mi][ct][3]) << 16);
            *(u32x2*)&Pp[w][mi][ct*256 + r16*16 + g*4] = pk;
          }
        }
        // ---- PV, V fragment shared across mi ----
        s16x8 pa0[2], pa1[2];
        #pragma unroll
        for (int ks2 = 0; ks2 < 2; ks2++) {
          const int poff = (ks2*2 + (g >> 1))*256 + r16*16 + (g & 1)*8;
          if (act0) pa0[ks2] = *(const s16x8*)&Pp[w][0][poff];
          pa1[ks2] = *(const s16x8*)&Pp[w][1][poff];
        }
        #pragma unroll
        for (int ks2 = 0; ks2 < 2; ks2++)
          #pragma unroll
          for (int dt = 0; dt < 8; dt++) {
            s16x8 vf = *(const s16x8*)&Vs[cur][(dt*16 + r16)*64 + ((ks2*32 + g*8) ^ swz)];
            if (act0) po[0][dt] = MFMA16(pa0[ks2], vf, po[0][dt]);
            po[1][dt] = MFMA16(pa1[ks2], vf, po[1][dt]);
          }
      }
      __builtin_amdgcn_s_barrier();
    }

    // ---- epilogue: normalize and write O (bf16) ----
    #pragma unroll
    for (int mi = 0; mi < 2; mi++) {
      float inv = 1.0f / lrow[mi];
      float invq[4];
      #pragma unroll
      for (int rr = 0; rr < 4; rr++) invq[rr] = __shfl(inv, g*4 + rr, 16);
      #pragma unroll
      for (int dt = 0; dt < 8; dt++)
        #pragma unroll
        for (int rr = 0; rr < 4; rr++) {
          long q = (long)q0 + mi*16 + g*4 + rr;
          Ob[((long)b*S_ + q)*H_ + h*D_ + dt*16 + r16] = f2bf(po[mi][dt][rr]*invq[rr]);
        }
    }
  }
}

// ---------- launcher ----------
extern "C" void kernel_launch(void* const* d_in, const int* in_sizes, int n_in,
                              void* d_out, int out_size, void* d_ws, size_t ws_size,
                              hipStream_t stream) {
  const float* hs = (const float*)d_in[0];
  const float* Wq = (const float*)d_in[1];
  const float* bq = (const float*)d_in[2];
  const float* Wk = (const float*)d_in[3];
  const float* bk = (const float*)d_in[4];
  const float* Wv = (const float*)d_in[5];
  const float* bv = (const float*)d_in[6];
  const float* Wc = (const float*)d_in[7];
  const float* bc = (const float*)d_in[8];

  float* out  = (float*)d_out;                  // (B,S,H)
  float* kout = out + (long)M_*H_;              // (B,S,NKV,D)
  float* vout = kout + (long)M_*NKV_*D_;        // (B,S,NKV,D)

  char* ws = (char*)d_ws;
  u16*  Xbf   = (u16*)ws;                                   // [4096][2048]
  u16*  Wqkvt = Xbf + (long)M_*H_;                          // [3072][2048]
  u16*  Wct   = Wqkvt + (long)NQKV_*H_;                     // [2048][2048]
  float* bqkv = (float*)(Wct + (long)H_*H_);                // [3072]
  float* QKV  = bqkv + NQKV_;                               // [4096][3072]
  float* cosb = QKV + (long)M_*NQKV_;                       // [2048][64]
  float* sinb = cosb + S_*64;
  u16*  Qbf   = (u16*)(sinb + S_*64);                       // [B][NQ][S][D] (pre-scaled)
  u16*  Kbf   = Qbf + (long)B_*NQ_*S_*D_;                   // [B][NKV][S][D]
  u16*  Vtb   = Kbf + (long)B_*NKV_*S_*D_;                  // [B][NKV][D][S]
  u16*  Obf   = Vtb + (long)B_*NKV_*D_*S_;                  // [4096][2048]

  cvt_x<<<2048, 256, 0, stream>>>(hs, Xbf, (long)M_*H_/4);
  wtrans<<<dim3(64,64), dim3(32,8), 0, stream>>>(Wq, Wqkvt, 2048, 2048);
  wtrans<<<dim3(16,64), dim3(32,8), 0, stream>>>(Wk, Wqkvt + 2048L*2048, 512, 2048);
  wtrans<<<dim3(16,64), dim3(32,8), 0, stream>>>(Wv, Wqkvt + 2560L*2048, 512, 2048);
  wtrans<<<dim3(64,64), dim3(32,8), 0, stream>>>(Wc, Wct, 2048, 2048);
  concat_bias<<<12, 256, 0, stream>>>(bq, bk, bv, bqkv);
  rope_tab<<<512, 256, 0, stream>>>(cosb, sinb);

  gemm_bt<<<dim3(NQKV_/128, M_/128), 256, 0, stream>>>(Xbf, Wqkvt, bqkv, QKV, M_, NQKV_, H_);
  rope_qkv<<<M_, 256, 0, stream>>>(QKV, cosb, sinb, Qbf, Kbf, kout, vout);
  vtrans<<<dim3(S_/32, D_/32, B_*NKV_), dim3(32,8), 0, stream>>>(QKV, Vtb);
  attn_kernel<<<dim3(256), 256, 0, stream>>>(Qbf, Kbf, Vtb, Obf);
  gemm_bt<<<dim3(H_/128, M_/128), 256, 0, stream>>>(Obf, Wct, bc, out, M_, H_, H_);
}

// Round 4
// 249.292 us; speedup vs baseline: 2.4595x; 1.1284x over previous
//
#include <hip/hip_runtime.h>
#include <math.h>

typedef unsigned short u16;
typedef __attribute__((ext_vector_type(8))) short s16x8;
typedef __attribute__((ext_vector_type(4))) float f32x4;
typedef __attribute__((ext_vector_type(2))) unsigned u32x2;

// ---------- constants ----------
#define B_  2
#define S_  2048
#define H_  2048
#define D_  128
#define NQ_ 16
#define NKV_ 4
#define M_  (B_*S_)        // 4096
#define NQKV_ 3072         // NQ*D + 2*NKV*D

#define MFMA16(a,b,c) __builtin_amdgcn_mfma_f32_16x16x32_bf16(a,b,c,0,0,0)

__device__ __forceinline__ u16 f2bf(float x) {
  union { float f; unsigned u; } v; v.f = x;
  unsigned r = v.u + 0x7fffu + ((v.u >> 16) & 1u);
  return (u16)(r >> 16);
}

// ---------- elementwise fp32 -> bf16 ----------
__global__ __launch_bounds__(256) void cvt_x(const float* __restrict__ X, u16* __restrict__ Xb, long n4) {
  const f32x4* X4 = (const f32x4*)X;
  for (long i = (long)blockIdx.x*256 + threadIdx.x; i < n4; i += (long)gridDim.x*256) {
    f32x4 v = X4[i];
    union { u16 u[4]; unsigned long long ll; } p;
    p.u[0] = f2bf(v[0]); p.u[1] = f2bf(v[1]); p.u[2] = f2bf(v[2]); p.u[3] = f2bf(v[3]);
    ((unsigned long long*)Xb)[i] = p.ll;
  }
}

// ---------- transpose + convert: W [K][N] fp32 -> Wt [N][K] bf16 ----------
__global__ __launch_bounds__(256) void wtrans(const float* __restrict__ W, u16* __restrict__ Wt,
                                              int N, int K) {
  __shared__ float t[32][33];
  const int n0 = blockIdx.x*32, k0 = blockIdx.y*32;
  const int tx = threadIdx.x, ty = threadIdx.y;   // (32,8)
  #pragma unroll
  for (int i = 0; i < 32; i += 8) t[ty+i][tx] = W[(long)(k0+ty+i)*N + n0 + tx];
  __syncthreads();
  #pragma unroll
  for (int i = 0; i < 32; i += 8) Wt[(long)(n0+ty+i)*K + k0 + tx] = f2bf(t[tx][ty+i]);
}

// ---------- V transpose: QKV fp32 v-part -> Vt bf16 [B][NKV][D][S] ----------
__global__ __launch_bounds__(256) void vtrans(const float* __restrict__ QKV, u16* __restrict__ Vt) {
  __shared__ float t[32][33];
  const int bk = blockIdx.z;            // b*4+kvh
  const int s0 = blockIdx.x*32, d0 = blockIdx.y*32;
  const int tx = threadIdx.x, ty = threadIdx.y;
  const int b = bk >> 2, kvh = bk & 3;
  #pragma unroll
  for (int i = 0; i < 32; i += 8)
    t[ty+i][tx] = QKV[(long)(b*S_ + s0+ty+i)*NQKV_ + 2560 + kvh*128 + d0 + tx];
  __syncthreads();
  #pragma unroll
  for (int i = 0; i < 32; i += 8)
    Vt[((long)bk*D_ + d0+ty+i)*S_ + s0 + tx] = f2bf(t[tx][ty+i]);
}

// ---------- bias concat ----------
__global__ void concat_bias(const float* bq, const float* bk, const float* bv, float* bqkv) {
  int i = blockIdx.x*256 + threadIdx.x;
  if (i < NQKV_)
    bqkv[i] = (i < 2048) ? bq[i] : ((i < 2560) ? bk[i-2048] : bv[i-2560]);
}

// ---------- rope tables ----------
__global__ void rope_tab(float* __restrict__ cosb, float* __restrict__ sinb) {
  int i = blockIdx.x*256 + threadIdx.x;   // 2048*64
  int t = i >> 6, d = i & 63;
  float inv = powf(10000.0f, -((float)(2*d)) * (1.0f/128.0f));
  float fr = (float)t * inv;
  float sv, cv;
  sincosf(fr, &sv, &cv);
  cosb[i] = cv; sinb[i] = sv;
}

// ---------- rope apply + scatter; Q pre-scaled by 1/sqrt(D)*log2(e) for exp2-domain softmax ----------
__global__ __launch_bounds__(256) void rope_qkv(
    const float* __restrict__ QKV, const float* __restrict__ cosb, const float* __restrict__ sinb,
    u16* __restrict__ Qb, u16* __restrict__ Kb,
    float* __restrict__ kout, float* __restrict__ vout)
{
  const float QS = 0.08838834764831845f * 1.4426950408889634f;
  const int m = blockIdx.x;                 // b*S + s
  const int b = m >> 11, s = m & 2047;
  const int tid = threadIdx.x;
  const float* row = QKV + (long)m * NQKV_;
  const int d = tid & 63;
  const float c  = cosb[s*64 + d];
  const float sn = sinb[s*64 + d];
  #pragma unroll
  for (int i = 0; i < 4; i++) {             // 16 q heads
    int hh = (tid + i*256) >> 6;
    float x1 = row[hh*128 + d], x2 = row[hh*128 + d + 64];
    float o1 = x1*c - x2*sn, o2 = x2*c + x1*sn;
    long base = ((long)(b*NQ_ + hh)*S_ + s)*D_;
    Qb[base + d] = f2bf(o1*QS);
    Qb[base + d + 64] = f2bf(o2*QS);
  }
  {                                          // 4 k heads
    int kh = tid >> 6;
    float x1 = row[2048 + kh*128 + d], x2 = row[2048 + kh*128 + d + 64];
    float o1 = x1*c - x2*sn, o2 = x2*c + x1*sn;
    long kb = ((long)(b*NKV_ + kh)*S_ + s)*D_;
    Kb[kb + d] = f2bf(o1);
    Kb[kb + d + 64] = f2bf(o2);
    long ko = ((long)m*NKV_ + kh)*D_;
    kout[ko + d] = o1;
    kout[ko + d + 64] = o2;
  }
  #pragma unroll
  for (int i = 0; i < 2; i++) {              // v passthrough
    int e = tid + i*256;
    vout[(long)m*512 + e] = row[2560 + e];
  }
}

// ---------- GEMM: C[M][N] = A[M][K](bf16) * B^T (B stored [N][K] bf16) + bias ----------
__global__ __launch_bounds__(256) void gemm_bt(
    const u16* __restrict__ A, const u16* __restrict__ B,
    const float* __restrict__ bias, float* __restrict__ C,
    int M, int N, int K)
{
  __shared__ u16 As[128*32];
  __shared__ u16 Bs[128*32];
  const int tid = threadIdx.x;
  const int lane = tid & 63, w = tid >> 6;
  const int r16 = lane & 15, g = lane >> 4;
  // XCD-aware bijective block swizzle (nwg % 8 == 0 for both call sites)
  const int gx = gridDim.x;
  const int nwg = gx * gridDim.y;
  const int id = blockIdx.y * gx + blockIdx.x;
  const int cpx = nwg >> 3;
  const int sid = (id & 7) * cpx + (id >> 3);
  const long m0 = (long)(sid / gx) * 128;
  const long n0 = (long)(sid % gx) * 128;
  const int wr = w >> 1, wc = w & 1;
  f32x4 acc[4][4] = {};

  const u16* Ag = A + m0 * K;
  const u16* Bg = B + n0 * K;

  for (int k0 = 0; k0 < K; k0 += 32) {
    #pragma unroll
    for (int it = 0; it < 2; it++) {
      int c = it*256 + w*64 + lane;
      const u16* ga = Ag + (long)(c >> 2) * K + k0 + (c & 3) * 8;
      __builtin_amdgcn_global_load_lds(
          (const __attribute__((address_space(1))) unsigned int*)ga,
          (__attribute__((address_space(3))) unsigned int*)&As[(it*256 + w*64)*8], 16, 0, 0);
      const u16* gb = Bg + (long)(c >> 2) * K + k0 + (c & 3) * 8;
      __builtin_amdgcn_global_load_lds(
          (const __attribute__((address_space(1))) unsigned int*)gb,
          (__attribute__((address_space(3))) unsigned int*)&Bs[(it*256 + w*64)*8], 16, 0, 0);
    }
    __syncthreads();
    s16x8 af[4], bf[4];
    #pragma unroll
    for (int mi = 0; mi < 4; mi++)
      af[mi] = *(const s16x8*)&As[(wr*64 + mi*16 + r16)*32 + g*8];
    #pragma unroll
    for (int nj = 0; nj < 4; nj++)
      bf[nj] = *(const s16x8*)&Bs[(wc*64 + nj*16 + r16)*32 + g*8];
    #pragma unroll
    for (int mi = 0; mi < 4; mi++)
      #pragma unroll
      for (int nj = 0; nj < 4; nj++)
        acc[mi][nj] = MFMA16(af[mi], bf[nj], acc[mi][nj]);
    __syncthreads();
  }

  #pragma unroll
  for (int mi = 0; mi < 4; mi++) {
    #pragma unroll
    for (int nj = 0; nj < 4; nj++) {
      int col = wc*64 + nj*16 + r16;
      float bv = bias[n0 + col];
      #pragma unroll
      for (int r = 0; r < 4; r++) {
        int row = wr*64 + mi*16 + g*4 + r;
        C[(m0 + row) * N + n0 + col] = acc[mi][nj][r] + bv;
      }
    }
  }
}

// ---------- flash attention v4 ----------
// 256 blocks (1/CU) x 512 threads (8 waves x 16 q-rows = 128-row tile).
// In-block pass pairing (qt, 15-qt): every block runs exactly 34 kv-steps.
// K/V double-buffered LDS via global_load_lds + counted vmcnt + raw s_barrier.
// Conflict-free P buffer: [q16][kv64] with 16B-granule XOR (gr^(q&7)) and
// 8B-half XOR (half^(q>>3)); writes/reads are bank-pair bijections per phase.
__global__ __launch_bounds__(512, 2) void attn_kernel(
    const u16* __restrict__ Qb, const u16* __restrict__ Kb,
    const u16* __restrict__ Vt, u16* __restrict__ Ob)
{
  __shared__ u16 Ks[2][64*128];      // [kv][d] swizzled
  __shared__ u16 Vs[2][128*64];      // [d][kv] swizzled
  __shared__ u16 Pp[8][1024];        // per-wave P, swizzled [q16][kv64]
  const int tid = threadIdx.x;
  const int lane = tid & 63, w = tid >> 6;     // 8 waves
  const int r16 = lane & 15, g = lane >> 4;
  const int l = blockIdx.x;          // 256 blocks
  const int bh = l >> 3;             // 0..31
  const int b = bh >> 4, h = bh & 15;
  const int pr = l & 7;
  const int kvh = h >> 2;
  const u16* Kg = Kb + ((long)(b*NKV_ + kvh))*S_*D_;
  const u16* Vg = Vt + ((long)(b*NKV_ + kvh))*D_*S_;
  const int swz = (r16 & 7) << 3;
  const int hf = (r16 >> 3);                   // 8B-half swizzle bit for P

  auto stage = [&](int buf, int kv0s) {
    #pragma unroll
    for (int j = 0; j < 2; j++) {
      const int i = w*2 + j;                   // 16 chunks across 8 waves
      const int krow = i*4 + (lane >> 4);
      const u16* gk = Kg + (long)(kv0s + krow)*D_ + (((lane & 15)*8) ^ ((krow & 7) << 3));
      __builtin_amdgcn_global_load_lds(
          (const __attribute__((address_space(1))) unsigned int*)gk,
          (__attribute__((address_space(3))) unsigned int*)&Ks[buf][i*512], 16, 0, 0);
      const int vrow = i*8 + (lane >> 3);
      const u16* gv = Vg + (long)vrow*S_ + kv0s + (((lane & 7)*8) ^ ((vrow & 7) << 3));
      __builtin_amdgcn_global_load_lds(
          (const __attribute__((address_space(1))) unsigned int*)gv,
          (__attribute__((address_space(3))) unsigned int*)&Vs[buf][i*512], 16, 0, 0);
    }
  };

  for (int pass = 0; pass < 2; pass++) {
    const int qt = pass ? (15 - pr) : pr;
    const int q0w = qt*128 + w*16;             // this wave's 16 q-rows
    const int nt = 2*qt + 2;
    const u16* Qg = Qb + (((long)(b*NQ_ + h))*S_ + q0w)*D_;
    s16x8 qf[4];
    #pragma unroll
    for (int ks = 0; ks < 4; ks++)
      qf[ks] = *(const s16x8*)&Qg[r16*D_ + ks*32 + g*8];
    f32x4 po[8] = {};
    float mrow = -1e30f, lrow = 0.f;

    stage(0, 0);
    for (int t = 0; t < nt; t++) {
      const int cur = t & 1;
      const int kv0 = t*64;
      if (t + 1 < nt) {
        stage(cur ^ 1, kv0 + 64);
        asm volatile("s_waitcnt vmcnt(4)" ::: "memory");
      } else {
        asm volatile("s_waitcnt vmcnt(0)" ::: "memory");
      }
      __builtin_amdgcn_s_barrier();

      if (kv0 <= q0w + 15) {
        // ---- QK^T (swapped): sc[ct][rr] = S[kv=kv0+ct*16+g*4+rr][q=q0w+r16] ----
        f32x4 sc[4] = {{0,0,0,0},{0,0,0,0},{0,0,0,0},{0,0,0,0}};
        #pragma unroll
        for (int ct = 0; ct < 4; ct++)
          #pragma unroll
          for (int ks = 0; ks < 4; ks++) {
            s16x8 kf = *(const s16x8*)&Ks[cur][(ct*16 + r16)*128 + ((ks*32 + g*8) ^ swz)];
            sc[ct] = MFMA16(kf, qf[ks], sc[ct]);
          }
        // ---- causal mask ----
        if (kv0 + 63 > q0w) {
          const int qrow = q0w + r16;
          #pragma unroll
          for (int ct = 0; ct < 4; ct++)
            #pragma unroll
            for (int rr = 0; rr < 4; rr++)
              if (kv0 + ct*16 + g*4 + rr > qrow) sc[ct][rr] = -3.0e38f;
        }
        // ---- online softmax (exp2 domain), row q=r16 ----
        float a0 = fmaxf(fmaxf(sc[0][0], sc[0][1]), fmaxf(sc[0][2], sc[0][3]));
        float a1 = fmaxf(fmaxf(sc[1][0], sc[1][1]), fmaxf(sc[1][2], sc[1][3]));
        float a2 = fmaxf(fmaxf(sc[2][0], sc[2][1]), fmaxf(sc[2][2], sc[2][3]));
        float a3 = fmaxf(fmaxf(sc[3][0], sc[3][1]), fmaxf(sc[3][2], sc[3][3]));
        float pm = fmaxf(fmaxf(a0, a1), fmaxf(a2, a3));
        pm = fmaxf(pm, __shfl_xor(pm, 16, 64));
        pm = fmaxf(pm, __shfl_xor(pm, 32, 64));
        float mn = mrow;
        if (!__all(pm - mn <= 8.0f)) {              // defer-max (T13)
          mn = fmaxf(mn, pm);
          float fr = exp2f(mrow - mn);
          mrow = mn;
          lrow *= fr;
          float frv[4];
          #pragma unroll
          for (int rr = 0; rr < 4; rr++) frv[rr] = __shfl(fr, g*4 + rr, 16);
          #pragma unroll
          for (int dt = 0; dt < 8; dt++)
            #pragma unroll
            for (int rr = 0; rr < 4; rr++) po[dt][rr] *= frv[rr];
        }
        float ps = 0.f;
        #pragma unroll
        for (int ct = 0; ct < 4; ct++)
          #pragma unroll
          for (int rr = 0; rr < 4; rr++) {
            float p = exp2f(sc[ct][rr] - mn);
            sc[ct][rr] = p;
            ps += p;
          }
        ps += __shfl_xor(ps, 16, 64);
        ps += __shfl_xor(ps, 32, 64);
        lrow += ps;
        // ---- P write: q=r16, kv=ct*16+g*4..+3 ; conflict-free swizzle ----
        #pragma unroll
        for (int ct = 0; ct < 4; ct++) {
          u32x2 pk;
          pk[0] = (unsigned)f2bf(sc[ct][0]) | ((unsigned)f2bf(sc[ct][1]) << 16);
          pk[1] = (unsigned)f2bf(sc[ct][2]) | ((unsigned)f2bf(sc[ct][3]) << 16);
          const int gr = ct*2 + (g >> 1);
          const int eo = r16*64 + ((gr ^ (r16 & 7))*8) + (((g & 1) ^ hf)*4);
          *(u32x2*)&Pp[w][eo] = pk;
        }
        // ---- P read: A-frag rows q=r16, kv=ks2*32+g*8..+7 (2x b64 each) ----
        s16x8 pa[2];
        #pragma unroll
        for (int ks2 = 0; ks2 < 2; ks2++) {
          const int base = r16*64 + (((ks2*4 + g) ^ (r16 & 7))*8);
          union { u32x2 q[2]; s16x8 v; } pu;
          pu.q[0] = *(const u32x2*)&Pp[w][base + (hf ? 4 : 0)];
          pu.q[1] = *(const u32x2*)&Pp[w][base + (hf ? 0 : 4)];
          pa[ks2] = pu.v;
        }
        // ---- PV: po[dt] = O[q=g*4+rr][d=dt*16+r16] ----
        #pragma unroll
        for (int ks2 = 0; ks2 < 2; ks2++)
          #pragma unroll
          for (int dt = 0; dt < 8; dt++) {
            s16x8 vf = *(const s16x8*)&Vs[cur][(dt*16 + r16)*64 + ((ks2*32 + g*8) ^ swz)];
            po[dt] = MFMA16(pa[ks2], vf, po[dt]);
          }
      }
      __builtin_amdgcn_s_barrier();
    }

    // ---- epilogue: normalize and write O (bf16) ----
    float inv = 1.0f / lrow;
    float invq[4];
    #pragma unroll
    for (int rr = 0; rr < 4; rr++) invq[rr] = __shfl(inv, g*4 + rr, 16);
    #pragma unroll
    for (int dt = 0; dt < 8; dt++)
      #pragma unroll
      for (int rr = 0; rr < 4; rr++) {
        long q = (long)q0w + g*4 + rr;
        Ob[((long)b*S_ + q)*H_ + h*D_ + dt*16 + r16] = f2bf(po[dt][rr]*invq[rr]);
      }
  }
}

// ---------- launcher ----------
extern "C" void kernel_launch(void* const* d_in, const int* in_sizes, int n_in,
                              void* d_out, int out_size, void* d_ws, size_t ws_size,
                              hipStream_t stream) {
  const float* hs = (const float*)d_in[0];
  const float* Wq = (const float*)d_in[1];
  const float* bq = (const float*)d_in[2];
  const float* Wk = (const float*)d_in[3];
  const float* bk = (const float*)d_in[4];
  const float* Wv = (const float*)d_in[5];
  const float* bv = (const float*)d_in[6];
  const float* Wc = (const float*)d_in[7];
  const float* bc = (const float*)d_in[8];

  float* out  = (float*)d_out;                  // (B,S,H)
  float* kout = out + (long)M_*H_;              // (B,S,NKV,D)
  float* vout = kout + (long)M_*NKV_*D_;        // (B,S,NKV,D)

  char* ws = (char*)d_ws;
  u16*  Xbf   = (u16*)ws;                                   // [4096][2048]
  u16*  Wqkvt = Xbf + (long)M_*H_;                          // [3072][2048]
  u16*  Wct   = Wqkvt + (long)NQKV_*H_;                     // [2048][2048]
  float* bqkv = (float*)(Wct + (long)H_*H_);                // [3072]
  float* QKV  = bqkv + NQKV_;                               // [4096][3072]
  float* cosb = QKV + (long)M_*NQKV_;                       // [2048][64]
  float* sinb = cosb + S_*64;
  u16*  Qbf   = (u16*)(sinb + S_*64);                       // [B][NQ][S][D] (pre-scaled)
  u16*  Kbf   = Qbf + (long)B_*NQ_*S_*D_;                   // [B][NKV][S][D]
  u16*  Vtb   = Kbf + (long)B_*NKV_*S_*D_;                  // [B][NKV][D][S]
  u16*  Obf   = Vtb + (long)B_*NKV_*D_*S_;                  // [4096][2048]

  cvt_x<<<2048, 256, 0, stream>>>(hs, Xbf, (long)M_*H_/4);
  wtrans<<<dim3(64,64), dim3(32,8), 0, stream>>>(Wq, Wqkvt, 2048, 2048);
  wtrans<<<dim3(16,64), dim3(32,8), 0, stream>>>(Wk, Wqkvt + 2048L*2048, 512, 2048);
  wtrans<<<dim3(16,64), dim3(32,8), 0, stream>>>(Wv, Wqkvt + 2560L*2048, 512, 2048);
  wtrans<<<dim3(64,64), dim3(32,8), 0, stream>>>(Wc, Wct, 2048, 2048);
  concat_bias<<<12, 256, 0, stream>>>(bq, bk, bv, bqkv);
  rope_tab<<<512, 256, 0, stream>>>(cosb, sinb);

  gemm_bt<<<dim3(NQKV_/128, M_/128), 256, 0, stream>>>(Xbf, Wqkvt, bqkv, QKV, M_, NQKV_, H_);
  rope_qkv<<<M_, 256, 0, stream>>>(QKV, cosb, sinb, Qbf, Kbf, kout, vout);
  vtrans<<<dim3(S_/32, D_/32, B_*NKV_), dim3(32,8), 0, stream>>>(QKV, Vtb);
  attn_kernel<<<dim3(256), 512, 0, stream>>>(Qbf, Kbf, Vtb, Obf);
  gemm_bt<<<dim3(H_/128, M_/128), 256, 0, stream>>>(Obf, Wct, bc, out, M_, H_, H_);
}

// Round 5
// 242.782 us; speedup vs baseline: 2.5255x; 1.0268x over previous
//
#include <hip/hip_runtime.h>
#include <math.h>

typedef unsigned short u16;
typedef __attribute__((ext_vector_type(8))) short s16x8;
typedef __attribute__((ext_vector_type(4))) float f32x4;
typedef __attribute__((ext_vector_type(16))) float f32x16;

// ---------- constants ----------
#define B_  2
#define S_  2048
#define H_  2048
#define D_  128
#define NQ_ 16
#define NKV_ 4
#define M_  (B_*S_)        // 4096
#define NQKV_ 3072         // NQ*D + 2*NKV*D

#define MFMA16(a,b,c) __builtin_amdgcn_mfma_f32_16x16x32_bf16(a,b,c,0,0,0)
#define MFMA32(a,b,c) __builtin_amdgcn_mfma_f32_32x32x16_bf16(a,b,c,0,0,0)

__device__ __forceinline__ u16 f2bf(float x) {
  union { float f; unsigned u; } v; v.f = x;
  unsigned r = v.u + 0x7fffu + ((v.u >> 16) & 1u);
  return (u16)(r >> 16);
}

__device__ __forceinline__ unsigned cvtpk(float lo, float hi) {
  unsigned r;
  asm("v_cvt_pk_bf16_f32 %0, %1, %2" : "=v"(r) : "v"(lo), "v"(hi));
  return r;
}

// ---------- elementwise fp32 -> bf16 ----------
__global__ __launch_bounds__(256) void cvt_x(const float* __restrict__ X, u16* __restrict__ Xb, long n4) {
  const f32x4* X4 = (const f32x4*)X;
  for (long i = (long)blockIdx.x*256 + threadIdx.x; i < n4; i += (long)gridDim.x*256) {
    f32x4 v = X4[i];
    union { u16 u[4]; unsigned long long ll; } p;
    p.u[0] = f2bf(v[0]); p.u[1] = f2bf(v[1]); p.u[2] = f2bf(v[2]); p.u[3] = f2bf(v[3]);
    ((unsigned long long*)Xb)[i] = p.ll;
  }
}

// ---------- transpose + convert: W [K][N] fp32 -> Wt [N][K] bf16 ----------
__global__ __launch_bounds__(256) void wtrans(const float* __restrict__ W, u16* __restrict__ Wt,
                                              int N, int K) {
  __shared__ float t[32][33];
  const int n0 = blockIdx.x*32, k0 = blockIdx.y*32;
  const int tx = threadIdx.x, ty = threadIdx.y;   // (32,8)
  #pragma unroll
  for (int i = 0; i < 32; i += 8) t[ty+i][tx] = W[(long)(k0+ty+i)*N + n0 + tx];
  __syncthreads();
  #pragma unroll
  for (int i = 0; i < 32; i += 8) Wt[(long)(n0+ty+i)*K + k0 + tx] = f2bf(t[tx][ty+i]);
}

// ---------- V transpose: QKV fp32 v-part -> Vt bf16 [B][NKV][D][S] ----------
__global__ __launch_bounds__(256) void vtrans(const float* __restrict__ QKV, u16* __restrict__ Vt) {
  __shared__ float t[32][33];
  const int bk = blockIdx.z;            // b*4+kvh
  const int s0 = blockIdx.x*32, d0 = blockIdx.y*32;
  const int tx = threadIdx.x, ty = threadIdx.y;
  const int b = bk >> 2, kvh = bk & 3;
  #pragma unroll
  for (int i = 0; i < 32; i += 8)
    t[ty+i][tx] = QKV[(long)(b*S_ + s0+ty+i)*NQKV_ + 2560 + kvh*128 + d0 + tx];
  __syncthreads();
  #pragma unroll
  for (int i = 0; i < 32; i += 8)
    Vt[((long)bk*D_ + d0+ty+i)*S_ + s0 + tx] = f2bf(t[tx][ty+i]);
}

// ---------- bias concat ----------
__global__ void concat_bias(const float* bq, const float* bk, const float* bv, float* bqkv) {
  int i = blockIdx.x*256 + threadIdx.x;
  if (i < NQKV_)
    bqkv[i] = (i < 2048) ? bq[i] : ((i < 2560) ? bk[i-2048] : bv[i-2560]);
}

// ---------- rope tables ----------
__global__ void rope_tab(float* __restrict__ cosb, float* __restrict__ sinb) {
  int i = blockIdx.x*256 + threadIdx.x;   // 2048*64
  int t = i >> 6, d = i & 63;
  float inv = powf(10000.0f, -((float)(2*d)) * (1.0f/128.0f));
  float fr = (float)t * inv;
  float sv, cv;
  sincosf(fr, &sv, &cv);
  cosb[i] = cv; sinb[i] = sv;
}

// ---------- rope apply + scatter; Q pre-scaled by 1/sqrt(D)*log2(e) for exp2-domain softmax ----------
__global__ __launch_bounds__(256) void rope_qkv(
    const float* __restrict__ QKV, const float* __restrict__ cosb, const float* __restrict__ sinb,
    u16* __restrict__ Qb, u16* __restrict__ Kb,
    float* __restrict__ kout, float* __restrict__ vout)
{
  const float QS = 0.08838834764831845f * 1.4426950408889634f;
  const int m = blockIdx.x;                 // b*S + s
  const int b = m >> 11, s = m & 2047;
  const int tid = threadIdx.x;
  const float* row = QKV + (long)m * NQKV_;
  const int d = tid & 63;
  const float c  = cosb[s*64 + d];
  const float sn = sinb[s*64 + d];
  #pragma unroll
  for (int i = 0; i < 4; i++) {             // 16 q heads
    int hh = (tid + i*256) >> 6;
    float x1 = row[hh*128 + d], x2 = row[hh*128 + d + 64];
    float o1 = x1*c - x2*sn, o2 = x2*c + x1*sn;
    long base = ((long)(b*NQ_ + hh)*S_ + s)*D_;
    Qb[base + d] = f2bf(o1*QS);
    Qb[base + d + 64] = f2bf(o2*QS);
  }
  {                                          // 4 k heads
    int kh = tid >> 6;
    float x1 = row[2048 + kh*128 + d], x2 = row[2048 + kh*128 + d + 64];
    float o1 = x1*c - x2*sn, o2 = x2*c + x1*sn;
    long kb = ((long)(b*NKV_ + kh)*S_ + s)*D_;
    Kb[kb + d] = f2bf(o1);
    Kb[kb + d + 64] = f2bf(o2);
    long ko = ((long)m*NKV_ + kh)*D_;
    kout[ko + d] = o1;
    kout[ko + d + 64] = o2;
  }
  #pragma unroll
  for (int i = 0; i < 2; i++) {              // v passthrough
    int e = tid + i*256;
    vout[(long)m*512 + e] = row[2560 + e];
  }
}

// ---------- GEMM: C[M][N] = A[M][K](bf16) * B^T (B stored [N][K] bf16) + bias ----------
__global__ __launch_bounds__(256) void gemm_bt(
    const u16* __restrict__ A, const u16* __restrict__ B,
    const float* __restrict__ bias, float* __restrict__ C,
    int M, int N, int K)
{
  __shared__ u16 As[128*32];
  __shared__ u16 Bs[128*32];
  const int tid = threadIdx.x;
  const int lane = tid & 63, w = tid >> 6;
  const int r16 = lane & 15, g = lane >> 4;
  // XCD-aware bijective block swizzle (nwg % 8 == 0 for both call sites)
  const int gx = gridDim.x;
  const int nwg = gx * gridDim.y;
  const int id = blockIdx.y * gx + blockIdx.x;
  const int cpx = nwg >> 3;
  const int sid = (id & 7) * cpx + (id >> 3);
  const long m0 = (long)(sid / gx) * 128;
  const long n0 = (long)(sid % gx) * 128;
  const int wr = w >> 1, wc = w & 1;
  f32x4 acc[4][4] = {};

  const u16* Ag = A + m0 * K;
  const u16* Bg = B + n0 * K;

  for (int k0 = 0; k0 < K; k0 += 32) {
    #pragma unroll
    for (int it = 0; it < 2; it++) {
      int c = it*256 + w*64 + lane;
      const u16* ga = Ag + (long)(c >> 2) * K + k0 + (c & 3) * 8;
      __builtin_amdgcn_global_load_lds(
          (const __attribute__((address_space(1))) unsigned int*)ga,
          (__attribute__((address_space(3))) unsigned int*)&As[(it*256 + w*64)*8], 16, 0, 0);
      const u16* gb = Bg + (long)(c >> 2) * K + k0 + (c & 3) * 8;
      __builtin_amdgcn_global_load_lds(
          (const __attribute__((address_space(1))) unsigned int*)gb,
          (__attribute__((address_space(3))) unsigned int*)&Bs[(it*256 + w*64)*8], 16, 0, 0);
    }
    __syncthreads();
    s16x8 af[4], bf[4];
    #pragma unroll
    for (int mi = 0; mi < 4; mi++)
      af[mi] = *(const s16x8*)&As[(wr*64 + mi*16 + r16)*32 + g*8];
    #pragma unroll
    for (int nj = 0; nj < 4; nj++)
      bf[nj] = *(const s16x8*)&Bs[(wc*64 + nj*16 + r16)*32 + g*8];
    #pragma unroll
    for (int mi = 0; mi < 4; mi++)
      #pragma unroll
      for (int nj = 0; nj < 4; nj++)
        acc[mi][nj] = MFMA16(af[mi], bf[nj], acc[mi][nj]);
    __syncthreads();
  }

  #pragma unroll
  for (int mi = 0; mi < 4; mi++) {
    #pragma unroll
    for (int nj = 0; nj < 4; nj++) {
      int col = wc*64 + nj*16 + r16;
      float bv = bias[n0 + col];
      #pragma unroll
      for (int r = 0; r < 4; r++) {
        int row = wr*64 + mi*16 + g*4 + r;
        C[(m0 + row) * N + n0 + col] = acc[mi][nj][r] + bv;
      }
    }
  }
}

// ---------- flash attention v5: 32x32 MFMA, 32 q-rows/wave, P fully in-register ----------
// 512 blocks x 256 threads (4 waves x 32 q-rows = 128-row tile), 2 blocks/CU (64KB LDS).
// qt-complement id mapping balances co-resident blocks. Swapped QK^T (mfma(K,Q)):
// lane owns P-row q=lane&31 (kv split across lane/lane+32); softmax in-register;
// P -> PV A-frags via cvt_pk_bf16 + shfl_xor(32), no P LDS. K swizzle 4-bit XOR.
__global__ __launch_bounds__(256, 2) void attn_kernel(
    const u16* __restrict__ Qb, const u16* __restrict__ Kb,
    const u16* __restrict__ Vt, u16* __restrict__ Ob)
{
  __shared__ u16 Ks[2][64*128];      // [kv][d], granule^(kv&15) swizzle
  __shared__ u16 Vs[2][128*64];      // [d][kv], granule^(d&7) swizzle
  const int tid = threadIdx.x;
  const int lane = tid & 63, w = tid >> 6;   // 4 waves
  const int l31 = lane & 31, hi = lane >> 5;
  const int id = blockIdx.x;                 // 512 blocks
  const int bh = id & 31;
  const int b = bh >> 4, h = bh & 15;
  const int p = id >> 5;                     // 0..15
  const int qt = (p < 8) ? p : (23 - p);     // ids c, c+256 complementary
  const int kvh = h >> 2;
  const int q0w = qt*128 + w*32;
  const int nt = 2*qt + 2;

  const u16* Qg = Qb + (((long)(b*NQ_ + h))*S_ + q0w)*D_;
  const u16* Kg = Kb + ((long)(b*NKV_ + kvh))*S_*D_;
  const u16* Vg = Vt + ((long)(b*NKV_ + kvh))*D_*S_;

  // Q fragments (B-operand of 32x32x16): lane holds q=l31, k = ks*16+hi*8+[0..7]
  s16x8 qf[8];
  #pragma unroll
  for (int ks = 0; ks < 8; ks++)
    qf[ks] = *(const s16x8*)&Qg[l31*D_ + ks*16 + hi*8];

  f32x16 po[4] = {};                 // O[q(reg)][d = dt*32 + l31]
  float mrow = -1e30f, lrow = 0.f;

  auto stage = [&](int buf, int kv0s) {
    #pragma unroll
    for (int i = 0; i < 4; i++) {
      const int c = i*4 + w;                 // 16 chunks of 1KB
      const int G = c*64 + lane;
      const int krow = G >> 4, kcg = G & 15;
      const u16* gk = Kg + (long)(kv0s + krow)*D_ + ((kcg ^ (krow & 15)) * 8);
      __builtin_amdgcn_global_load_lds(
          (const __attribute__((address_space(1))) unsigned int*)gk,
          (__attribute__((address_space(3))) unsigned int*)&Ks[buf][c*512], 16, 0, 0);
      const int vrow = G >> 3, vcg = G & 7;
      const u16* gv = Vg + (long)vrow*S_ + kv0s + ((vcg ^ (vrow & 7)) * 8);
      __builtin_amdgcn_global_load_lds(
          (const __attribute__((address_space(1))) unsigned int*)gv,
          (__attribute__((address_space(3))) unsigned int*)&Vs[buf][c*512], 16, 0, 0);
    }
  };

  stage(0, 0);
  for (int t = 0; t < nt; t++) {
    const int cur = t & 1;
    const int kv0 = t*64;
    if (t + 1 < nt) {
      stage(cur ^ 1, kv0 + 64);
      asm volatile("s_waitcnt vmcnt(8)" ::: "memory");
    } else {
      asm volatile("s_waitcnt vmcnt(0)" ::: "memory");
    }
    __builtin_amdgcn_s_barrier();

    if (kv0 <= q0w + 31) {
      // ---- QK^T swapped: sc[ct] = S[kv = kv0+ct*32+rowmap(r,hi)][q = l31] ----
      f32x16 sc[2] = {};
      #pragma unroll
      for (int ks = 0; ks < 8; ks++) {
        #pragma unroll
        for (int ct = 0; ct < 2; ct++) {
          const int row = ct*32 + l31;
          s16x8 kf = *(const s16x8*)&Ks[cur][row*128 + ((ks*16 + hi*8) ^ ((row & 15)*8))];
          sc[ct] = MFMA32(kf, qf[ks], sc[ct]);
        }
      }
      // ---- causal mask (rowmap(r,hi) = (r&3)+8*(r>>2)+4*hi) ----
      if (kv0 + 63 > q0w) {
        const int qrow = q0w + l31;
        #pragma unroll
        for (int ct = 0; ct < 2; ct++)
          #pragma unroll
          for (int r = 0; r < 16; r++) {
            int kv = kv0 + ct*32 + (r & 3) + 8*(r >> 2) + 4*hi;
            if (kv > qrow) sc[ct][r] = -3.0e38f;
          }
      }
      // ---- online softmax (exp2 domain), row q = l31 ----
      float pm = sc[0][0];
      #pragma unroll
      for (int ct = 0; ct < 2; ct++)
        #pragma unroll
        for (int r = 0; r < 16; r++) pm = fmaxf(pm, sc[ct][r]);
      pm = fmaxf(pm, __shfl_xor(pm, 32, 64));
      if (!__all(pm - mrow <= 8.0f)) {       // defer-max (T13)
        float mn = fmaxf(mrow, pm);
        float fr = exp2f(mrow - mn);
        mrow = mn;
        lrow *= fr;
        #pragma unroll
        for (int r = 0; r < 16; r++) {
          float frv = __shfl(fr, (r & 3) + 8*(r >> 2) + 4*hi, 64);
          #pragma unroll
          for (int dt = 0; dt < 4; dt++) po[dt][r] *= frv;
        }
      }
      float ps = 0.f;
      #pragma unroll
      for (int ct = 0; ct < 2; ct++)
        #pragma unroll
        for (int r = 0; r < 16; r++) {
          float pv = exp2f(sc[ct][r] - mrow);
          sc[ct][r] = pv;
          ps += pv;
        }
      ps += __shfl_xor(ps, 32, 64);
      lrow += ps;
      // ---- pack P to bf16 + cross-half exchange -> PV A-frags (no LDS) ----
      unsigned mw[2][8], ex[2][8];
      #pragma unroll
      for (int ct = 0; ct < 2; ct++)
        #pragma unroll
        for (int wd = 0; wd < 8; wd++)
          mw[ct][wd] = cvtpk(sc[ct][2*wd], sc[ct][2*wd + 1]);
      #pragma unroll
      for (int ct = 0; ct < 2; ct++)
        #pragma unroll
        for (int wd = 0; wd < 8; wd++)
          ex[ct][wd] = __shfl_xor((int)mw[ct][wd], 32, 64);
      s16x8 pa[4];
      #pragma unroll
      for (int ct = 0; ct < 2; ct++)
        #pragma unroll
        for (int pp = 0; pp < 2; pp++) {
          union { unsigned u[4]; s16x8 v; } pu;
          pu.u[0] = hi ? ex[ct][4*pp + 2] : mw[ct][4*pp + 0];
          pu.u[1] = hi ? ex[ct][4*pp + 3] : mw[ct][4*pp + 1];
          pu.u[2] = hi ? mw[ct][4*pp + 2] : ex[ct][4*pp + 0];
          pu.u[3] = hi ? mw[ct][4*pp + 3] : ex[ct][4*pp + 1];
          pa[ct*2 + pp] = pu.v;
        }
      // ---- PV: po[dt] += P(A) * V(B) ----
      #pragma unroll
      for (int ks2 = 0; ks2 < 4; ks2++)
        #pragma unroll
        for (int dt = 0; dt < 4; dt++) {
          const int row = dt*32 + l31;
          s16x8 vf = *(const s16x8*)&Vs[cur][row*64 + ((ks2*16 + hi*8) ^ ((row & 7)*8))];
          po[dt] = MFMA32(pa[ks2], vf, po[dt]);
        }
    }
    __builtin_amdgcn_s_barrier();
  }

  // ---- epilogue: normalize and write O (bf16) ----
  float inv = 1.0f / lrow;
  #pragma unroll
  for (int r = 0; r < 16; r++) {
    const int qr = (r & 3) + 8*(r >> 2) + 4*hi;
    float invq = __shfl(inv, qr, 64);
    const long q = (long)q0w + qr;
    #pragma unroll
    for (int dt = 0; dt < 4; dt++)
      Ob[((long)b*S_ + q)*H_ + h*D_ + dt*32 + l31] = f2bf(po[dt][r]*invq);
  }
}

// ---------- launcher ----------
extern "C" void kernel_launch(void* const* d_in, const int* in_sizes, int n_in,
                              void* d_out, int out_size, void* d_ws, size_t ws_size,
                              hipStream_t stream) {
  const float* hs = (const float*)d_in[0];
  const float* Wq = (const float*)d_in[1];
  const float* bq = (const float*)d_in[2];
  const float* Wk = (const float*)d_in[3];
  const float* bk = (const float*)d_in[4];
  const float* Wv = (const float*)d_in[5];
  const float* bv = (const float*)d_in[6];
  const float* Wc = (const float*)d_in[7];
  const float* bc = (const float*)d_in[8];

  float* out  = (float*)d_out;                  // (B,S,H)
  float* kout = out + (long)M_*H_;              // (B,S,NKV,D)
  float* vout = kout + (long)M_*NKV_*D_;        // (B,S,NKV,D)

  char* ws = (char*)d_ws;
  u16*  Xbf   = (u16*)ws;                                   // [4096][2048]
  u16*  Wqkvt = Xbf + (long)M_*H_;                          // [3072][2048]
  u16*  Wct   = Wqkvt + (long)NQKV_*H_;                     // [2048][2048]
  float* bqkv = (float*)(Wct + (long)H_*H_);                // [3072]
  float* QKV  = bqkv + NQKV_;                               // [4096][3072]
  float* cosb = QKV + (long)M_*NQKV_;                       // [2048][64]
  float* sinb = cosb + S_*64;
  u16*  Qbf   = (u16*)(sinb + S_*64);                       // [B][NQ][S][D] (pre-scaled)
  u16*  Kbf   = Qbf + (long)B_*NQ_*S_*D_;                   // [B][NKV][S][D]
  u16*  Vtb   = Kbf + (long)B_*NKV_*S_*D_;                  // [B][NKV][D][S]
  u16*  Obf   = Vtb + (long)B_*NKV_*D_*S_;                  // [4096][2048]

  cvt_x<<<2048, 256, 0, stream>>>(hs, Xbf, (long)M_*H_/4);
  wtrans<<<dim3(64,64), dim3(32,8), 0, stream>>>(Wq, Wqkvt, 2048, 2048);
  wtrans<<<dim3(16,64), dim3(32,8), 0, stream>>>(Wk, Wqkvt + 2048L*2048, 512, 2048);
  wtrans<<<dim3(16,64), dim3(32,8), 0, stream>>>(Wv, Wqkvt + 2560L*2048, 512, 2048);
  wtrans<<<dim3(64,64), dim3(32,8), 0, stream>>>(Wc, Wct, 2048, 2048);
  concat_bias<<<12, 256, 0, stream>>>(bq, bk, bv, bqkv);
  rope_tab<<<512, 256, 0, stream>>>(cosb, sinb);

  gemm_bt<<<dim3(NQKV_/128, M_/128), 256, 0, stream>>>(Xbf, Wqkvt, bqkv, QKV, M_, NQKV_, H_);
  rope_qkv<<<M_, 256, 0, stream>>>(QKV, cosb, sinb, Qbf, Kbf, kout, vout);
  vtrans<<<dim3(S_/32, D_/32, B_*NKV_), dim3(32,8), 0, stream>>>(QKV, Vtb);
  attn_kernel<<<dim3(512), 256, 0, stream>>>(Qbf, Kbf, Vtb, Obf);
  gemm_bt<<<dim3(H_/128, M_/128), 256, 0, stream>>>(Obf, Wct, bc, out, M_, H_, H_);
}

// Round 6
// 229.340 us; speedup vs baseline: 2.6735x; 1.0586x over previous
//
#include <hip/hip_runtime.h>
#include <math.h>

typedef unsigned short u16;
typedef __attribute__((ext_vector_type(8))) short s16x8;
typedef __attribute__((ext_vector_type(4))) float f32x4;
typedef __attribute__((ext_vector_type(16))) float f32x16;

// ---------- constants ----------
#define B_  2
#define S_  2048
#define H_  2048
#define D_  128
#define NQ_ 16
#define NKV_ 4
#define M_  (B_*S_)        // 4096
#define NQKV_ 3072         // NQ*D + 2*NKV*D

#define MFMA16(a,b,c) __builtin_amdgcn_mfma_f32_16x16x32_bf16(a,b,c,0,0,0)
#define MFMA32(a,b,c) __builtin_amdgcn_mfma_f32_32x32x16_bf16(a,b,c,0,0,0)

__device__ __forceinline__ u16 f2bf(float x) {
  union { float f; unsigned u; } v; v.f = x;
  unsigned r = v.u + 0x7fffu + ((v.u >> 16) & 1u);
  return (u16)(r >> 16);
}
__device__ __forceinline__ float bf2f(u16 x) {
  union { unsigned u; float f; } v; v.u = ((unsigned)x) << 16;
  return v.f;
}

__device__ __forceinline__ unsigned cvtpk(float lo, float hi) {
  unsigned r;
  asm("v_cvt_pk_bf16_f32 %0, %1, %2" : "=v"(r) : "v"(lo), "v"(hi));
  return r;
}

// ---------- elementwise fp32 -> bf16 ----------
__global__ __launch_bounds__(256) void cvt_x(const float* __restrict__ X, u16* __restrict__ Xb, long n4) {
  const f32x4* X4 = (const f32x4*)X;
  for (long i = (long)blockIdx.x*256 + threadIdx.x; i < n4; i += (long)gridDim.x*256) {
    f32x4 v = X4[i];
    union { u16 u[4]; unsigned long long ll; } p;
    p.u[0] = f2bf(v[0]); p.u[1] = f2bf(v[1]); p.u[2] = f2bf(v[2]); p.u[3] = f2bf(v[3]);
    ((unsigned long long*)Xb)[i] = p.ll;
  }
}

// ---------- transpose + convert: W [K][N] fp32 -> Wt [N][K] bf16 ----------
__global__ __launch_bounds__(256) void wtrans(const float* __restrict__ W, u16* __restrict__ Wt,
                                              int N, int K) {
  __shared__ float t[32][33];
  const int n0 = blockIdx.x*32, k0 = blockIdx.y*32;
  const int tx = threadIdx.x, ty = threadIdx.y;   // (32,8)
  #pragma unroll
  for (int i = 0; i < 32; i += 8) t[ty+i][tx] = W[(long)(k0+ty+i)*N + n0 + tx];
  __syncthreads();
  #pragma unroll
  for (int i = 0; i < 32; i += 8) Wt[(long)(n0+ty+i)*K + k0 + tx] = f2bf(t[tx][ty+i]);
}

// ---------- V transpose: QKV bf16 v-part -> Vt bf16 [B][NKV][D][S] ----------
__global__ __launch_bounds__(256) void vtrans(const u16* __restrict__ QKV, u16* __restrict__ Vt) {
  __shared__ u16 t[32][33];
  const int bk = blockIdx.z;            // b*4+kvh
  const int s0 = blockIdx.x*32, d0 = blockIdx.y*32;
  const int tx = threadIdx.x, ty = threadIdx.y;
  const int b = bk >> 2, kvh = bk & 3;
  #pragma unroll
  for (int i = 0; i < 32; i += 8)
    t[ty+i][tx] = QKV[(long)(b*S_ + s0+ty+i)*NQKV_ + 2560 + kvh*128 + d0 + tx];
  __syncthreads();
  #pragma unroll
  for (int i = 0; i < 32; i += 8)
    Vt[((long)bk*D_ + d0+ty+i)*S_ + s0 + tx] = t[tx][ty+i];
}

// ---------- bias concat ----------
__global__ void concat_bias(const float* bq, const float* bk, const float* bv, float* bqkv) {
  int i = blockIdx.x*256 + threadIdx.x;
  if (i < NQKV_)
    bqkv[i] = (i < 2048) ? bq[i] : ((i < 2560) ? bk[i-2048] : bv[i-2560]);
}

// ---------- rope tables ----------
__global__ void rope_tab(float* __restrict__ cosb, float* __restrict__ sinb) {
  int i = blockIdx.x*256 + threadIdx.x;   // 2048*64
  int t = i >> 6, d = i & 63;
  float inv = powf(10000.0f, -((float)(2*d)) * (1.0f/128.0f));
  float fr = (float)t * inv;
  float sv, cv;
  sincosf(fr, &sv, &cv);
  cosb[i] = cv; sinb[i] = sv;
}

// ---------- rope apply + scatter; QKV now bf16; Q pre-scaled for exp2-domain softmax ----------
__global__ __launch_bounds__(256) void rope_qkv(
    const u16* __restrict__ QKV, const float* __restrict__ cosb, const float* __restrict__ sinb,
    u16* __restrict__ Qb, u16* __restrict__ Kb,
    float* __restrict__ kout, float* __restrict__ vout)
{
  const float QS = 0.08838834764831845f * 1.4426950408889634f;
  const int m = blockIdx.x;                 // b*S + s
  const int b = m >> 11, s = m & 2047;
  const int tid = threadIdx.x;
  const u16* row = QKV + (long)m * NQKV_;
  const int d = tid & 63;
  const float c  = cosb[s*64 + d];
  const float sn = sinb[s*64 + d];
  #pragma unroll
  for (int i = 0; i < 4; i++) {             // 16 q heads
    int hh = (tid + i*256) >> 6;
    float x1 = bf2f(row[hh*128 + d]), x2 = bf2f(row[hh*128 + d + 64]);
    float o1 = x1*c - x2*sn, o2 = x2*c + x1*sn;
    long base = ((long)(b*NQ_ + hh)*S_ + s)*D_;
    Qb[base + d] = f2bf(o1*QS);
    Qb[base + d + 64] = f2bf(o2*QS);
  }
  {                                          // 4 k heads
    int kh = tid >> 6;
    float x1 = bf2f(row[2048 + kh*128 + d]), x2 = bf2f(row[2048 + kh*128 + d + 64]);
    float o1 = x1*c - x2*sn, o2 = x2*c + x1*sn;
    long kb = ((long)(b*NKV_ + kh)*S_ + s)*D_;
    Kb[kb + d] = f2bf(o1);
    Kb[kb + d + 64] = f2bf(o2);
    long ko = ((long)m*NKV_ + kh)*D_;
    kout[ko + d] = o1;
    kout[ko + d + 64] = o2;
  }
  #pragma unroll
  for (int i = 0; i < 2; i++) {              // v passthrough
    int e = tid + i*256;
    vout[(long)m*512 + e] = bf2f(row[2560 + e]);
  }
}

// ---------- GEMM 256-tile, deep pipeline ----------
// C[M][N] = A[M][K](bf16) * B^T (B stored [N][K] bf16) + bias.
// BM=256, BN in {256,128}, BK=64, 512 threads = 8 waves.
// LDS: 2 K-tile double buffer, XOR-swizzled (granule ^ (row&7)) via pre-swizzled
// global source (rule 21). Counted vmcnt: 2 tiles prefetched ahead, never drains
// to 0 in the main loop (T3/T4). Raw s_barrier. setprio around MFMA (T5).
template<int BN, typename OutT>
__global__ __launch_bounds__(512, 2) void gemm256(
    const u16* __restrict__ A, const u16* __restrict__ Bm,
    const float* __restrict__ bias, OutT* __restrict__ C,
    int M, int N, int K)
{
  __shared__ u16 As[2][256*64];
  __shared__ u16 Bs[2][BN*64];
  constexpr int WCc = (BN == 256) ? 4 : 2;        // waves along N
  constexpr int MI  = (BN == 256) ? 8 : 4;        // 16-row M frags per wave
  constexpr int LB  = BN/64;                      // B stage rounds
  constexpr int TOT = 4 + LB;                     // loads/thread per K-tile

  const int tid = threadIdx.x;
  const int lane = tid & 63, w = tid >> 6;
  const int r16 = lane & 15, g = lane >> 4;
  const int wrn = w / WCc, wcn = w % WCc;
  const int abase = wrn * (MI*16);
  const int bbase = wcn * 64;

  // XCD-aware bijective swizzle (nwg % 8 == 0 at both call sites)
  const int gx = gridDim.x;
  const int nwg = gx * gridDim.y;
  const int id = blockIdx.y * gx + blockIdx.x;
  const int cpx = nwg >> 3;
  const int sid = (id & 7) * cpx + (id >> 3);
  const long m0 = (long)(sid / gx) * 256;
  const long n0 = (long)(sid % gx) * BN;

  const u16* Ag = A + m0 * K;
  const u16* Bg = Bm + n0 * K;

  auto stage = [&](int buf, int k0) {
    #pragma unroll
    for (int i = 0; i < 4; i++) {
      const int slot = i*512 + tid;
      const int row = slot >> 3, cg = slot & 7;
      const u16* src = Ag + (long)row*K + k0 + ((cg ^ (row & 7)) * 8);
      __builtin_amdgcn_global_load_lds(
          (const __attribute__((address_space(1))) unsigned int*)src,
          (__attribute__((address_space(3))) unsigned int*)&As[buf][slot*8], 16, 0, 0);
    }
    #pragma unroll
    for (int i = 0; i < LB; i++) {
      const int slot = i*512 + tid;
      const int row = slot >> 3, cg = slot & 7;
      const u16* src = Bg + (long)row*K + k0 + ((cg ^ (row & 7)) * 8);
      __builtin_amdgcn_global_load_lds(
          (const __attribute__((address_space(1))) unsigned int*)src,
          (__attribute__((address_space(3))) unsigned int*)&Bs[buf][slot*8], 16, 0, 0);
    }
  };

  f32x4 acc[MI][4] = {};
  const int nt = K >> 6;

  stage(0, 0);
  stage(1, 64);
  for (int t = 0; t < nt; t++) {
    if (t + 1 < nt) {
      if constexpr (TOT == 8) asm volatile("s_waitcnt vmcnt(8)" ::: "memory");
      else                    asm volatile("s_waitcnt vmcnt(6)" ::: "memory");
    } else {
      asm volatile("s_waitcnt vmcnt(0)" ::: "memory");
    }
    __builtin_amdgcn_s_barrier();

    const u16* as = &As[t & 1][0];
    const u16* bs = &Bs[t & 1][0];
    #pragma unroll
    for (int k = 0; k < 2; k++) {
      s16x8 bfr[4];
      #pragma unroll
      for (int nj = 0; nj < 4; nj++) {
        const int R = bbase + nj*16 + r16;
        bfr[nj] = *(const s16x8*)&bs[R*64 + (((k*4 + g) ^ (R & 7)) * 8)];
      }
      __builtin_amdgcn_s_setprio(1);
      #pragma unroll
      for (int mi = 0; mi < MI; mi++) {
        const int R = abase + mi*16 + r16;
        s16x8 afr = *(const s16x8*)&as[R*64 + (((k*4 + g) ^ (R & 7)) * 8)];
        #pragma unroll
        for (int nj = 0; nj < 4; nj++)
          acc[mi][nj] = MFMA16(afr, bfr[nj], acc[mi][nj]);
      }
      __builtin_amdgcn_s_setprio(0);
    }
    __builtin_amdgcn_s_barrier();
    if (t + 2 < nt) stage(t & 1, (t + 2) << 6);
  }

  // ---- epilogue: bias + store ----
  #pragma unroll
  for (int mi = 0; mi < MI; mi++) {
    #pragma unroll
    for (int nj = 0; nj < 4; nj++) {
      const int col = bbase + nj*16 + r16;
      const float bv = bias[n0 + col];
      #pragma unroll
      for (int r = 0; r < 4; r++) {
        const long row = m0 + abase + mi*16 + g*4 + r;
        if constexpr (sizeof(OutT) == 2)
          C[row * N + n0 + col] = (OutT)f2bf(acc[mi][nj][r] + bv);
        else
          C[row * N + n0 + col] = (OutT)(acc[mi][nj][r] + bv);
      }
    }
  }
}

// ---------- flash attention v5: 32x32 MFMA, 32 q-rows/wave, P fully in-register ----------
__global__ __launch_bounds__(256, 2) void attn_kernel(
    const u16* __restrict__ Qb, const u16* __restrict__ Kb,
    const u16* __restrict__ Vt, u16* __restrict__ Ob)
{
  __shared__ u16 Ks[2][64*128];      // [kv][d], granule^(kv&15) swizzle
  __shared__ u16 Vs[2][128*64];      // [d][kv], granule^(d&7) swizzle
  const int tid = threadIdx.x;
  const int lane = tid & 63, w = tid >> 6;   // 4 waves
  const int l31 = lane & 31, hi = lane >> 5;
  const int id = blockIdx.x;                 // 512 blocks
  const int bh = id & 31;
  const int b = bh >> 4, h = bh & 15;
  const int p = id >> 5;                     // 0..15
  const int qt = (p < 8) ? p : (23 - p);     // ids c, c+256 complementary
  const int kvh = h >> 2;
  const int q0w = qt*128 + w*32;
  const int nt = 2*qt + 2;

  const u16* Qg = Qb + (((long)(b*NQ_ + h))*S_ + q0w)*D_;
  const u16* Kg = Kb + ((long)(b*NKV_ + kvh))*S_*D_;
  const u16* Vg = Vt + ((long)(b*NKV_ + kvh))*D_*S_;

  s16x8 qf[8];
  #pragma unroll
  for (int ks = 0; ks < 8; ks++)
    qf[ks] = *(const s16x8*)&Qg[l31*D_ + ks*16 + hi*8];

  f32x16 po[4] = {};                 // O[q(reg)][d = dt*32 + l31]
  float mrow = -1e30f, lrow = 0.f;

  auto stage = [&](int buf, int kv0s) {
    #pragma unroll
    for (int i = 0; i < 4; i++) {
      const int c = i*4 + w;                 // 16 chunks of 1KB
      const int G = c*64 + lane;
      const int krow = G >> 4, kcg = G & 15;
      const u16* gk = Kg + (long)(kv0s + krow)*D_ + ((kcg ^ (krow & 15)) * 8);
      __builtin_amdgcn_global_load_lds(
          (const __attribute__((address_space(1))) unsigned int*)gk,
          (__attribute__((address_space(3))) unsigned int*)&Ks[buf][c*512], 16, 0, 0);
      const int vrow = G >> 3, vcg = G & 7;
      const u16* gv = Vg + (long)vrow*S_ + kv0s + ((vcg ^ (vrow & 7)) * 8);
      __builtin_amdgcn_global_load_lds(
          (const __attribute__((address_space(1))) unsigned int*)gv,
          (__attribute__((address_space(3))) unsigned int*)&Vs[buf][c*512], 16, 0, 0);
    }
  };

  stage(0, 0);
  for (int t = 0; t < nt; t++) {
    const int cur = t & 1;
    const int kv0 = t*64;
    if (t + 1 < nt) {
      stage(cur ^ 1, kv0 + 64);
      asm volatile("s_waitcnt vmcnt(8)" ::: "memory");
    } else {
      asm volatile("s_waitcnt vmcnt(0)" ::: "memory");
    }
    __builtin_amdgcn_s_barrier();

    if (kv0 <= q0w + 31) {
      f32x16 sc[2] = {};
      #pragma unroll
      for (int ks = 0; ks < 8; ks++) {
        #pragma unroll
        for (int ct = 0; ct < 2; ct++) {
          const int row = ct*32 + l31;
          s16x8 kf = *(const s16x8*)&Ks[cur][row*128 + ((ks*16 + hi*8) ^ ((row & 15)*8))];
          sc[ct] = MFMA32(kf, qf[ks], sc[ct]);
        }
      }
      if (kv0 + 63 > q0w) {
        const int qrow = q0w + l31;
        #pragma unroll
        for (int ct = 0; ct < 2; ct++)
          #pragma unroll
          for (int r = 0; r < 16; r++) {
            int kv = kv0 + ct*32 + (r & 3) + 8*(r >> 2) + 4*hi;
            if (kv > qrow) sc[ct][r] = -3.0e38f;
          }
      }
      float pm = sc[0][0];
      #pragma unroll
      for (int ct = 0; ct < 2; ct++)
        #pragma unroll
        for (int r = 0; r < 16; r++) pm = fmaxf(pm, sc[ct][r]);
      pm = fmaxf(pm, __shfl_xor(pm, 32, 64));
      if (!__all(pm - mrow <= 8.0f)) {       // defer-max (T13)
        float mn = fmaxf(mrow, pm);
        float fr = exp2f(mrow - mn);
        mrow = mn;
        lrow *= fr;
        #pragma unroll
        for (int r = 0; r < 16; r++) {
          float frv = __shfl(fr, (r & 3) + 8*(r >> 2) + 4*hi, 64);
          #pragma unroll
          for (int dt = 0; dt < 4; dt++) po[dt][r] *= frv;
        }
      }
      float ps = 0.f;
      #pragma unroll
      for (int ct = 0; ct < 2; ct++)
        #pragma unroll
        for (int r = 0; r < 16; r++) {
          float pv = exp2f(sc[ct][r] - mrow);
          sc[ct][r] = pv;
          ps += pv;
        }
      ps += __shfl_xor(ps, 32, 64);
      lrow += ps;
      unsigned mw[2][8], ex[2][8];
      #pragma unroll
      for (int ct = 0; ct < 2; ct++)
        #pragma unroll
        for (int wd = 0; wd < 8; wd++)
          mw[ct][wd] = cvtpk(sc[ct][2*wd], sc[ct][2*wd + 1]);
      #pragma unroll
      for (int ct = 0; ct < 2; ct++)
        #pragma unroll
        for (int wd = 0; wd < 8; wd++)
          ex[ct][wd] = __shfl_xor((int)mw[ct][wd], 32, 64);
      s16x8 pa[4];
      #pragma unroll
      for (int ct = 0; ct < 2; ct++)
        #pragma unroll
        for (int pp = 0; pp < 2; pp++) {
          union { unsigned u[4]; s16x8 v; } pu;
          pu.u[0] = hi ? ex[ct][4*pp + 2] : mw[ct][4*pp + 0];
          pu.u[1] = hi ? ex[ct][4*pp + 3] : mw[ct][4*pp + 1];
          pu.u[2] = hi ? mw[ct][4*pp + 2] : ex[ct][4*pp + 0];
          pu.u[3] = hi ? mw[ct][4*pp + 3] : ex[ct][4*pp + 1];
          pa[ct*2 + pp] = pu.v;
        }
      #pragma unroll
      for (int ks2 = 0; ks2 < 4; ks2++)
        #pragma unroll
        for (int dt = 0; dt < 4; dt++) {
          const int row = dt*32 + l31;
          s16x8 vf = *(const s16x8*)&Vs[cur][row*64 + ((ks2*16 + hi*8) ^ ((row & 7)*8))];
          po[dt] = MFMA32(pa[ks2], vf, po[dt]);
        }
    }
    __builtin_amdgcn_s_barrier();
  }

  float inv = 1.0f / lrow;
  #pragma unroll
  for (int r = 0; r < 16; r++) {
    const int qr = (r & 3) + 8*(r >> 2) + 4*hi;
    float invq = __shfl(inv, qr, 64);
    const long q = (long)q0w + qr;
    #pragma unroll
    for (int dt = 0; dt < 4; dt++)
      Ob[((long)b*S_ + q)*H_ + h*D_ + dt*32 + l31] = f2bf(po[dt][r]*invq);
  }
}

// ---------- launcher ----------
extern "C" void kernel_launch(void* const* d_in, const int* in_sizes, int n_in,
                              void* d_out, int out_size, void* d_ws, size_t ws_size,
                              hipStream_t stream) {
  const float* hs = (const float*)d_in[0];
  const float* Wq = (const float*)d_in[1];
  const float* bq = (const float*)d_in[2];
  const float* Wk = (const float*)d_in[3];
  const float* bk = (const float*)d_in[4];
  const float* Wv = (const float*)d_in[5];
  const float* bv = (const float*)d_in[6];
  const float* Wc = (const float*)d_in[7];
  const float* bc = (const float*)d_in[8];

  float* out  = (float*)d_out;                  // (B,S,H)
  float* kout = out + (long)M_*H_;              // (B,S,NKV,D)
  float* vout = kout + (long)M_*NKV_*D_;        // (B,S,NKV,D)

  char* ws = (char*)d_ws;
  u16*  Xbf   = (u16*)ws;                                   // [4096][2048]
  u16*  Wqkvt = Xbf + (long)M_*H_;                          // [3072][2048]
  u16*  Wct   = Wqkvt + (long)NQKV_*H_;                     // [2048][2048]
  float* bqkv = (float*)(Wct + (long)H_*H_);                // [3072]
  u16*  QKV   = (u16*)(bqkv + NQKV_);                       // [4096][3072] bf16
  float* cosb = (float*)(QKV + (long)M_*NQKV_);             // [2048][64]
  float* sinb = cosb + S_*64;
  u16*  Qbf   = (u16*)(sinb + S_*64);                       // [B][NQ][S][D] (pre-scaled)
  u16*  Kbf   = Qbf + (long)B_*NQ_*S_*D_;                   // [B][NKV][S][D]
  u16*  Vtb   = Kbf + (long)B_*NKV_*S_*D_;                  // [B][NKV][D][S]
  u16*  Obf   = Vtb + (long)B_*NKV_*D_*S_;                  // [4096][2048]

  cvt_x<<<2048, 256, 0, stream>>>(hs, Xbf, (long)M_*H_/4);
  wtrans<<<dim3(64,64), dim3(32,8), 0, stream>>>(Wq, Wqkvt, 2048, 2048);
  wtrans<<<dim3(16,64), dim3(32,8), 0, stream>>>(Wk, Wqkvt + 2048L*2048, 512, 2048);
  wtrans<<<dim3(16,64), dim3(32,8), 0, stream>>>(Wv, Wqkvt + 2560L*2048, 512, 2048);
  wtrans<<<dim3(64,64), dim3(32,8), 0, stream>>>(Wc, Wct, 2048, 2048);
  concat_bias<<<12, 256, 0, stream>>>(bq, bk, bv, bqkv);
  rope_tab<<<512, 256, 0, stream>>>(cosb, sinb);

  gemm256<256, u16><<<dim3(NQKV_/256, M_/256), 512, 0, stream>>>(
      Xbf, Wqkvt, bqkv, QKV, M_, NQKV_, H_);
  rope_qkv<<<M_, 256, 0, stream>>>(QKV, cosb, sinb, Qbf, Kbf, kout, vout);
  vtrans<<<dim3(S_/32, D_/32, B_*NKV_), dim3(32,8), 0, stream>>>(QKV, Vtb);
  attn_kernel<<<dim3(512), 256, 0, stream>>>(Qbf, Kbf, Vtb, Obf);
  gemm256<128, float><<<dim3(H_/128, M_/256), 512, 0, stream>>>(
      Obf, Wct, bc, out, M_, H_, H_);
}